// Round 3
// baseline (514.546 us; speedup 1.0000x reference)
//
#include <hip/hip_runtime.h>
#include <hip/hip_bf16.h>
#include <math.h>

// MEGConformerLayer: conv block + DeBERTa-v2 attention + FFN, all bf16 MFMA.
// B=8 S=1024 D=512 H=8 DH=64 K=3 FF=1024 BUCKETS=32 SPAN=32
// R3: flash v3 (global K/VT frags, no per-tile barriers, gather fast path),
//     gemm 128x64 tiles, fused weight convert, VT pre-transpose.

#define B_  8
#define S_  1024
#define D_  512
#define H_  8
#define DH_ 64
#define FF_ 1024
#define BS_ (B_*S_)   // 8192

typedef __attribute__((ext_vector_type(8))) short  short8;
typedef __attribute__((ext_vector_type(4))) short  short4v;
typedef __attribute__((ext_vector_type(4))) float  f32x4;
typedef __attribute__((ext_vector_type(4))) int    int4v;

static __device__ __forceinline__ float b2f(short u){
  union { int i; float f; } cv; cv.i = ((int)(unsigned short)u) << 16; return cv.f;
}
static __device__ __forceinline__ short f2b(float f){
  union { float f; unsigned u; } cv; cv.f = f;
  unsigned r = cv.u + 0x7FFFu + ((cv.u >> 16) & 1u);  // RNE
  return (short)(r >> 16);
}
static __device__ __forceinline__ float silu_f(float x){
  return x / (1.f + __expf(-x));
}
static __device__ __forceinline__ f32x4 mfma16(short8 a, short8 b, f32x4 c){
  return __builtin_amdgcn_mfma_f32_16x16x32_bf16(a, b, c, 0, 0, 0);
}

// ---------------- fused fp32 -> bf16 weight convert (8 segments, 1 launch) ----------------
struct F2B8 { const float* s[8]; short* d[8]; int n[8]; };
__global__ __launch_bounds__(256) void f2b8_kernel(F2B8 a){
  int seg = blockIdx.y;
  int i = (blockIdx.x*256 + threadIdx.x)*4;
  if (i >= a.n[seg]) return;
  float4 v = *(const float4*)(a.s[seg] + i);
  short4v o; o.x = f2b(v.x); o.y = f2b(v.y); o.z = f2b(v.z); o.w = f2b(v.w);
  *(short4v*)(a.d[seg] + i) = o;
}

// ---------------- DeBERTa log-bucket index table: delta=i-j in [-1023,1024] ----------------
__global__ __launch_bounds__(256) void tab_kernel(signed char* __restrict__ tab){
  int t = blockIdx.x*256 + threadIdx.x;
  if (t >= 2048) return;
  int d = t - 1023;
  int ad = d < 0 ? -d : d;
  int bkt;
  if (ad <= 16) bkt = d;
  else {
    const float inv_log = 15.f / logf(7.9375f);   // (mid-1)/log((MAX_REL-1)/mid)
    float lp = ceilf(logf((float)ad * (1.f/16.f)) * inv_log) + 16.f;
    int ilp = (int)lp;
    bkt = (d > 0) ? ilp : -ilp;
  }
  int idx = bkt + 32;
  idx = idx < 0 ? 0 : (idx > 63 ? 63 : idx);
  tab[t] = (signed char)idx;
}

// ---------------- LayerNorm (rows of 512), fp32 in -> bf16 out ----------------
__global__ __launch_bounds__(128) void ln_kernel(const float* __restrict__ x,
                                                 const float* __restrict__ g,
                                                 const float* __restrict__ bb,
                                                 short* __restrict__ out){
  int row = blockIdx.x;
  int tid = threadIdx.x;               // 128 threads * float4 = 512
  float4 v = ((const float4*)(x + (size_t)row*D_))[tid];
  float s  = v.x + v.y + v.z + v.w;
  float ss = v.x*v.x + v.y*v.y + v.z*v.z + v.w*v.w;
  #pragma unroll
  for (int off = 32; off; off >>= 1){ s += __shfl_down(s, off); ss += __shfl_down(ss, off); }
  __shared__ float red[4];
  if ((tid & 63) == 0){ red[tid>>6] = s; red[2 + (tid>>6)] = ss; }
  __syncthreads();
  float S  = red[0] + red[1];
  float SS = red[2] + red[3];
  float m   = S * (1.f/D_);
  float var = SS * (1.f/D_) - m*m;
  float rs  = rsqrtf(var + 1e-5f);
  float4 gv = ((const float4*)g)[tid];
  float4 bv = ((const float4*)bb)[tid];
  short4v o;
  o.x = f2b((v.x - m)*rs*gv.x + bv.x);
  o.y = f2b((v.y - m)*rs*gv.y + bv.y);
  o.z = f2b((v.z - m)*rs*gv.z + bv.z);
  o.w = f2b((v.w - m)*rs*gv.w + bv.w);
  *(short4v*)(out + (size_t)row*D_ + tid*4) = o;
}

// ---------------- depthwise conv (K=3, pad 1, per-seq) + SiLU, bf16->bf16 ----------------
__global__ __launch_bounds__(256) void dwconv_kernel(const short* __restrict__ xn,
                                                     const float* __restrict__ w,   // [D,1,3]
                                                     const float* __restrict__ bias,
                                                     short* __restrict__ out){
  int idx = blockIdx.x*256 + threadIdx.x;   // BS_*64 threads, 8 channels each
  int bs  = idx >> 6;
  int d8  = (idx & 63) << 3;
  int s   = bs & (S_-1);
  const short* base = xn + (size_t)bs*D_ + d8;
  short8 z = {};
  short8 xm = (s > 0)     ? *(const short8*)(base - D_) : z;
  short8 xc =               *(const short8*)(base);
  short8 xp = (s < S_-1)  ? *(const short8*)(base + D_) : z;
  short8 o;
  #pragma unroll
  for (int i = 0; i < 8; i++){
    int d = d8 + i;
    float acc = bias[d] + b2f(xm[i])*w[d*3+0] + b2f(xc[i])*w[d*3+1] + b2f(xp[i])*w[d*3+2];
    o[i] = f2b(silu_f(acc));
  }
  *(short8*)(out + (size_t)bs*D_ + d8) = o;
}

// ---------------- GEMM 128Mx64N tile, BK=64, 4 waves (2x2), each 64Mx32N ----------------
// C[m,n] = sum_k A[m,k]*W[n,k] + bias[n] (+silu)(+res). res/of32 may alias
// (same-thread read-before-write per element).
template<bool SILU, bool RES, bool OF32, bool OBF>
__global__ __launch_bounds__(256) void gemm128_kernel(const short* __restrict__ A,
                                                      const short* __restrict__ W,
                                                      const float* __restrict__ bias,
                                                      const float* res,
                                                      float* of32,
                                                      short* __restrict__ obf,
                                                      int M, int N, int K){
  __shared__ short a_lds[128][72];
  __shared__ short b_lds[64][72];
  int tid = threadIdx.x;
  int w = tid >> 6, lane = tid & 63, quad = lane >> 4, l16 = lane & 15;
  int wm = (w >> 1) * 64, wn = (w & 1) * 32;
  int m0 = blockIdx.y * 128, n0 = blockIdx.x * 64;
  f32x4 acc[4][2] = {};
  for (int kk = 0; kk < K; kk += 64){
    #pragma unroll
    for (int i = 0; i < 4; i++){               // A tile: 128x64 = 1024 chunks
      int c = i*256 + tid;
      int r = c >> 3, cc = (c & 7) * 8;
      *(int4v*)&a_lds[r][cc] = *(const int4v*)(A + (size_t)(m0+r)*K + kk + cc);
    }
    #pragma unroll
    for (int i = 0; i < 2; i++){               // B tile: 64x64 = 512 chunks
      int c = i*256 + tid;
      int r = c >> 3, cc = (c & 7) * 8;
      *(int4v*)&b_lds[r][cc] = *(const int4v*)(W + (size_t)(n0+r)*K + kk + cc);
    }
    __syncthreads();
    #pragma unroll
    for (int ks = 0; ks < 2; ks++){
      short8 b0 = *(const short8*)&b_lds[wn      + l16][ks*32 + quad*8];
      short8 b1 = *(const short8*)&b_lds[wn + 16 + l16][ks*32 + quad*8];
      #pragma unroll
      for (int mt = 0; mt < 4; mt++){
        short8 a = *(const short8*)&a_lds[wm + mt*16 + l16][ks*32 + quad*8];
        acc[mt][0] = mfma16(a, b0, acc[mt][0]);
        acc[mt][1] = mfma16(a, b1, acc[mt][1]);
      }
    }
    __syncthreads();
  }
  #pragma unroll
  for (int mt = 0; mt < 4; mt++)
    #pragma unroll
    for (int nt = 0; nt < 2; nt++)
      #pragma unroll
      for (int r = 0; r < 4; r++){
        int row = m0 + wm + mt*16 + quad*4 + r;
        int col = n0 + wn + nt*16 + l16;
        float val = acc[mt][nt][r] + bias[col];
        if (SILU) val = silu_f(val);
        if (RES)  val += res[(size_t)row*N + col];
        if (OF32) of32[(size_t)row*N + col] = val;
        if (OBF)  obf[(size_t)row*N + col] = f2b(val);
      }
}

// ---------------- GEMM 64x64 (kept for the two tiny M=64 pos-projection gemms) ----------------
template<bool SILU, bool RES, bool OF32, bool OBF>
__global__ __launch_bounds__(256) void gemm_kernel(const short* __restrict__ A,
                                                   const short* __restrict__ W,
                                                   const float* __restrict__ bias,
                                                   const float* res,
                                                   float* of32,
                                                   short* __restrict__ obf,
                                                   int M, int N, int K){
  __shared__ short a_lds[64][72];
  __shared__ short b_lds[64][72];
  int tid = threadIdx.x;
  int w = tid >> 6, lane = tid & 63, quad = lane >> 4, l16 = lane & 15;
  int wm = (w >> 1) * 32, wn = (w & 1) * 32;
  int m0 = blockIdx.y * 64, n0 = blockIdx.x * 64;
  int r0 = tid >> 3, c0 = (tid & 7) * 8;
  int r1 = r0 + 32;
  f32x4 acc[2][2] = {};
  for (int kk = 0; kk < K; kk += 64){
    *(int4v*)&a_lds[r0][c0] = *(const int4v*)(A + (size_t)(m0+r0)*K + kk + c0);
    *(int4v*)&a_lds[r1][c0] = *(const int4v*)(A + (size_t)(m0+r1)*K + kk + c0);
    *(int4v*)&b_lds[r0][c0] = *(const int4v*)(W + (size_t)(n0+r0)*K + kk + c0);
    *(int4v*)&b_lds[r1][c0] = *(const int4v*)(W + (size_t)(n0+r1)*K + kk + c0);
    __syncthreads();
    #pragma unroll
    for (int ks = 0; ks < 2; ks++){
      short8 a0 = *(const short8*)&a_lds[wm      + l16][ks*32 + quad*8];
      short8 a1 = *(const short8*)&a_lds[wm + 16 + l16][ks*32 + quad*8];
      short8 b0 = *(const short8*)&b_lds[wn      + l16][ks*32 + quad*8];
      short8 b1 = *(const short8*)&b_lds[wn + 16 + l16][ks*32 + quad*8];
      acc[0][0] = mfma16(a0, b0, acc[0][0]);
      acc[0][1] = mfma16(a0, b1, acc[0][1]);
      acc[1][0] = mfma16(a1, b0, acc[1][0]);
      acc[1][1] = mfma16(a1, b1, acc[1][1]);
    }
    __syncthreads();
  }
  #pragma unroll
  for (int mt = 0; mt < 2; mt++)
    #pragma unroll
    for (int nt = 0; nt < 2; nt++)
      #pragma unroll
      for (int r = 0; r < 4; r++){
        int row = m0 + wm + mt*16 + quad*4 + r;
        int col = n0 + wn + nt*16 + l16;
        float val = acc[mt][nt][r] + bias[col];
        if (SILU) val = silu_f(val);
        if (RES)  val += res[(size_t)row*N + col];
        if (OF32) of32[(size_t)row*N + col] = val;
        if (OBF)  obf[(size_t)row*N + col] = f2b(val);
      }
}

// ---------------- c2p/p2c position-bias batched GEMM ----------------
__global__ __launch_bounds__(256) void posbias_kernel(const short* __restrict__ q,
                                                      const short* __restrict__ k,
                                                      const short* __restrict__ posk,
                                                      const short* __restrict__ posq,
                                                      short* __restrict__ c2p,
                                                      short* __restrict__ p2c){
  int bsT = blockIdx.x;          // 128 tiles of 64 rows
  int h   = blockIdx.y;
  int tid = threadIdx.x, w = tid >> 6, lane = tid & 63, quad = lane >> 4, l16 = lane & 15;
  int row_a = bsT*64 + w*16 + l16;
  f32x4 accc[4] = {}, accp[4] = {};
  #pragma unroll
  for (int ks = 0; ks < 2; ks++){
    short8 aq = *(const short8*)(q + (size_t)row_a*D_ + h*DH_ + ks*32 + quad*8);
    short8 ak = *(const short8*)(k + (size_t)row_a*D_ + h*DH_ + ks*32 + quad*8);
    #pragma unroll
    for (int nt = 0; nt < 4; nt++){
      short8 bk = *(const short8*)(posk + (size_t)(nt*16+l16)*D_ + h*DH_ + ks*32 + quad*8);
      short8 bq = *(const short8*)(posq + (size_t)(nt*16+l16)*D_ + h*DH_ + ks*32 + quad*8);
      accc[nt] = mfma16(aq, bk, accc[nt]);
      accp[nt] = mfma16(ak, bq, accp[nt]);
    }
  }
  #pragma unroll
  for (int nt = 0; nt < 4; nt++)
    #pragma unroll
    for (int r = 0; r < 4; r++){
      int row = bsT*64 + w*16 + quad*4 + r;
      int col = h*DH_ + nt*16 + l16;
      c2p[(size_t)row*D_ + col] = f2b(accc[nt][r]);
      p2c[(size_t)row*D_ + col] = f2b(accp[nt][r]);
    }
}

// ---------------- V -> VT[B,H,DH,S] pre-transpose (65-pad: 2-way conflicts = free) ------
__global__ __launch_bounds__(256) void vtrans_kernel(const short* __restrict__ v,
                                                     short* __restrict__ vt){
  __shared__ short t_lds[64][65];
  int st = blockIdx.x, h = blockIdx.y, b = blockIdx.z;
  int s0 = st*64;
  int tid = threadIdx.x;
  #pragma unroll
  for (int i = 0; i < 2; i++){
    int c = i*256 + tid;
    int s = c >> 3, d8 = (c & 7) * 8;
    short8 vv = *(const short8*)(v + (size_t)(b*S_ + s0 + s)*D_ + h*DH_ + d8);
    #pragma unroll
    for (int jj = 0; jj < 8; jj++) t_lds[d8+jj][s] = vv[jj];
  }
  __syncthreads();
  #pragma unroll
  for (int i = 0; i < 2; i++){
    int c = i*256 + tid;
    int d = c >> 3, s8 = (c & 7) * 8;
    short8 o;
    #pragma unroll
    for (int jj = 0; jj < 8; jj++) o[jj] = t_lds[d][s8+jj];
    *(short8*)(vt + ((size_t)(b*H_ + h)*DH_ + d)*S_ + s0 + s8) = o;
  }
}

// ---------------- flash attention v3: barrier-free K-loop, gather fast path ----------------
// block = (i-tile 64, h, b); 4 waves x 16 Q rows; K/VT fragments straight from
// global (L1/L2-resident tiles); P round-trip via wave-private LDS band.
__global__ __launch_bounds__(256) void flash_kernel(const short* __restrict__ q,
                                                    const short* __restrict__ k,
                                                    const short* __restrict__ VT,
                                                    const short* __restrict__ c2p,
                                                    const short* __restrict__ p2c,
                                                    const signed char* __restrict__ TAB,
                                                    short* __restrict__ ctx){
  __shared__ short c2p_lds[64][72];
  __shared__ short p_lds[64][72];
  __shared__ signed char tab[2048];
  int it = blockIdx.x, h = blockIdx.y, b = blockIdx.z;
  int i0 = it * 64;
  int tid = threadIdx.x, w = tid >> 6, lane = tid & 63, quad = lane >> 4, l16 = lane & 15;
  const float scale = 0.07216878364f;   // 1/sqrt(DH*3)

  ((unsigned long long*)tab)[tid] = ((const unsigned long long*)TAB)[tid];  // 2048 B
  #pragma unroll
  for (int i = 0; i < 2; i++){
    int c = i*256 + tid;
    int r = c >> 3, cc = (c & 7) * 8;
    *(int4v*)&c2p_lds[r][cc] = *(const int4v*)(c2p + (size_t)(b*S_ + i0 + r)*D_ + h*DH_ + cc);
  }
  short8 qf0, qf1;
  {
    size_t row = (size_t)(b*S_ + i0 + w*16 + l16);
    qf0 = *(const short8*)(q + row*D_ + h*DH_ +      quad*8);
    qf1 = *(const short8*)(q + row*D_ + h*DH_ + 32 + quad*8);
  }
  __syncthreads();

  float cpos[4], cneg[4];
  #pragma unroll
  for (int r = 0; r < 4; r++){
    int iloc = w*16 + quad*4 + r;
    cpos[r] = b2f(c2p_lds[iloc][63]);   // saturated idx for i-j >= 128
    cneg[r] = b2f(c2p_lds[iloc][0]);    // saturated idx for i-j <= -128
  }
  f32x4 o_acc[4] = {};
  float mrow[4] = {-INFINITY, -INFINITY, -INFINITY, -INFINITY};
  float lrow[4] = {};
  const short* Kbase  = k   + (size_t)(b*S_)*D_ + h*DH_;
  const short* VTbase = VT  + (size_t)(b*H_ + h)*DH_*S_;
  const short* Pbase  = p2c + (size_t)(b*S_)*D_ + h*DH_;

  for (int jt = 0; jt < 16; jt++){
    int j0 = jt * 64;
    // S = Q K^T (per wave: 16 rows x 64 cols), K-frags direct from global
    f32x4 sfr[4];
    #pragma unroll
    for (int nt = 0; nt < 4; nt++){
      const short* kr = Kbase + (size_t)(j0 + nt*16 + l16)*D_ + quad*8;
      f32x4 a = {};
      a = mfma16(qf0, *(const short8*)(kr), a);
      a = mfma16(qf1, *(const short8*)(kr + 32), a);
      sfr[nt] = a;
    }
    float sval[4][4];
    if (jt >= it-2 && jt <= it+2){
      // near-diagonal: full log-bucket gather (c2p from LDS, p2c from global)
      #pragma unroll
      for (int nt = 0; nt < 4; nt++){
        int jloc = nt*16 + l16;
        const short* pr = Pbase + (size_t)(j0 + jloc)*D_;
        #pragma unroll
        for (int r = 0; r < 4; r++){
          int iloc = w*16 + quad*4 + r;
          int idx  = tab[(i0 + iloc) - (j0 + jloc) + 1023];
          sval[nt][r] = (sfr[nt][r] + b2f(c2p_lds[iloc][idx]) + b2f(pr[idx])) * scale;
        }
      }
    } else {
      // far: bucket index saturated (|i-j| >= 129 guaranteed) -> constant idx
      int cidx = (jt < it) ? 63 : 0;
      const float* cP = (jt < it) ? cpos : cneg;
      #pragma unroll
      for (int nt = 0; nt < 4; nt++){
        float pv = b2f(Pbase[(size_t)(j0 + nt*16 + l16)*D_ + cidx]);
        #pragma unroll
        for (int r = 0; r < 4; r++)
          sval[nt][r] = (sfr[nt][r] + cP[r] + pv) * scale;
      }
    }
    // online softmax (rows live in 16-lane groups: shfl-xor 8,4,2,1)
    float mnew[4], alpha[4], lsum[4];
    #pragma unroll
    for (int r = 0; r < 4; r++){
      float mx = fmaxf(fmaxf(sval[0][r], sval[1][r]), fmaxf(sval[2][r], sval[3][r]));
      #pragma unroll
      for (int off = 8; off; off >>= 1) mx = fmaxf(mx, __shfl_xor(mx, off));
      mnew[r]  = fmaxf(mrow[r], mx);
      alpha[r] = __expf(mrow[r] - mnew[r]);
      lsum[r]  = 0.f;
    }
    #pragma unroll
    for (int nt = 0; nt < 4; nt++)
      #pragma unroll
      for (int r = 0; r < 4; r++){
        float p = __expf(sval[nt][r] - mnew[r]);
        sval[nt][r] = p;
        lsum[r] += p;
      }
    #pragma unroll
    for (int r = 0; r < 4; r++){
      #pragma unroll
      for (int off = 8; off; off >>= 1) lsum[r] += __shfl_xor(lsum[r], off);
      lrow[r] = lrow[r]*alpha[r] + lsum[r];
      mrow[r] = mnew[r];
    }
    // P: C-layout -> A-layout via wave-private LDS band (no barrier needed)
    #pragma unroll
    for (int nt = 0; nt < 4; nt++)
      #pragma unroll
      for (int r = 0; r < 4; r++)
        p_lds[w*16 + quad*4 + r][nt*16 + l16] = f2b(sval[nt][r]);
    #pragma unroll
    for (int nt = 0; nt < 4; nt++)
      #pragma unroll
      for (int r = 0; r < 4; r++) o_acc[nt][r] *= alpha[r];
    short8 pf0 = *(const short8*)&p_lds[w*16 + l16][     quad*8];
    short8 pf1 = *(const short8*)&p_lds[w*16 + l16][32 + quad*8];
    // O += P V, VT-frags direct from global
    #pragma unroll
    for (int nt = 0; nt < 4; nt++){
      const short* vr = VTbase + (size_t)(nt*16 + l16)*S_ + j0 + quad*8;
      o_acc[nt] = mfma16(pf0, *(const short8*)(vr), o_acc[nt]);
      o_acc[nt] = mfma16(pf1, *(const short8*)(vr + 32), o_acc[nt]);
    }
  }
  #pragma unroll
  for (int nt = 0; nt < 4; nt++)
    #pragma unroll
    for (int r = 0; r < 4; r++){
      size_t row = (size_t)(b*S_ + i0 + w*16 + quad*4 + r);
      ctx[row*D_ + h*DH_ + nt*16 + l16] = f2b(o_acc[nt][r] / lrow[r]);
    }
}

// ---------------- workspace layout (bytes) — high-water 55,248,896 (~52.7 MB) ----------------
// Aliases: DWS = C2P span (dead before posbias); VT = XN span (XN dead after
// q/k/v gemms, rewritten by ln3 after flash); CTX = V span (V dead after
// vtrans); FFH = Q..K span (dead after flash); fp32 residual chain in d_out.
static const size_t OFF_XN   = 0;           // bf16 8192x512  (alias: VT)
static const size_t OFF_Q    = 8388608;     // bf16 8192x512  (alias: FFH lo)
static const size_t OFF_K    = 16777216;    // bf16 8192x512  (alias: FFH hi)
static const size_t OFF_V    = 25165824;    // bf16 8192x512  (alias: CTX)
static const size_t OFF_C2P  = 33554432;    // bf16 8192x512  (alias: DWS)
static const size_t OFF_P2C  = 41943040;    // bf16 8192x512
static const size_t OFF_WPW  = 50331648;    // bf16 512x512
static const size_t OFF_WQ   = 50855936;
static const size_t OFF_WK   = 51380224;
static const size_t OFF_WV   = 51904512;
static const size_t OFF_WO   = 52428800;
static const size_t OFF_W1   = 52953088;    // bf16 1024x512
static const size_t OFF_W2   = 54001664;    // bf16 512x1024
static const size_t OFF_REL  = 55050240;    // bf16 64x512
static const size_t OFF_POSK = 55115776;    // bf16 64x512
static const size_t OFF_POSQ = 55181312;    // bf16 64x512
static const size_t OFF_TAB  = 55246848;    // int8 2048

extern "C" void kernel_launch(void* const* d_in, const int* in_sizes, int n_in,
                              void* d_out, int out_size, void* d_ws, size_t ws_size,
                              hipStream_t stream){
  const float* x    = (const float*)d_in[0];
  const float* ln1g = (const float*)d_in[1];
  const float* ln1b = (const float*)d_in[2];
  const float* dww  = (const float*)d_in[3];
  const float* dwb  = (const float*)d_in[4];
  const float* pww  = (const float*)d_in[5];
  const float* pwb  = (const float*)d_in[6];
  const float* ln2g = (const float*)d_in[7];
  const float* ln2b = (const float*)d_in[8];
  const float* qw   = (const float*)d_in[9];
  const float* qb   = (const float*)d_in[10];
  const float* kw   = (const float*)d_in[11];
  const float* kb   = (const float*)d_in[12];
  const float* vw   = (const float*)d_in[13];
  const float* vb   = (const float*)d_in[14];
  const float* ow   = (const float*)d_in[15];
  const float* ob   = (const float*)d_in[16];
  const float* rel  = (const float*)d_in[17];
  const float* ln3g = (const float*)d_in[18];
  const float* ln3b = (const float*)d_in[19];
  const float* w1   = (const float*)d_in[20];
  const float* b1   = (const float*)d_in[21];
  const float* w2   = (const float*)d_in[22];
  const float* b2   = (const float*)d_in[23];
  float* out = (float*)d_out;
  char* ws = (char*)d_ws;

  short* XN   = (short*)(ws + OFF_XN);
  short* Q    = (short*)(ws + OFF_Q);
  short* Kb_  = (short*)(ws + OFF_K);
  short* V    = (short*)(ws + OFF_V);
  short* C2P  = (short*)(ws + OFF_C2P);
  short* P2C  = (short*)(ws + OFF_P2C);
  short* WPW  = (short*)(ws + OFF_WPW);
  short* WQ   = (short*)(ws + OFF_WQ);
  short* WK   = (short*)(ws + OFF_WK);
  short* WV   = (short*)(ws + OFF_WV);
  short* WO   = (short*)(ws + OFF_WO);
  short* W1B  = (short*)(ws + OFF_W1);
  short* W2B  = (short*)(ws + OFF_W2);
  short* RELB = (short*)(ws + OFF_REL);
  short* POSK = (short*)(ws + OFF_POSK);
  short* POSQ = (short*)(ws + OFF_POSQ);
  signed char* TAB = (signed char*)(ws + OFF_TAB);
  short* DWS  = C2P;     // alias
  short* VT   = XN;      // alias
  short* CTX  = V;       // alias
  short* FFH  = Q;       // alias (16 MB over Q+K)

  // fused weight conversions + bucket table
  F2B8 fa;
  fa.s[0]=pww; fa.d[0]=WPW; fa.n[0]=262144;
  fa.s[1]=qw;  fa.d[1]=WQ;  fa.n[1]=262144;
  fa.s[2]=kw;  fa.d[2]=WK;  fa.n[2]=262144;
  fa.s[3]=vw;  fa.d[3]=WV;  fa.n[3]=262144;
  fa.s[4]=ow;  fa.d[4]=WO;  fa.n[4]=262144;
  fa.s[5]=w1;  fa.d[5]=W1B; fa.n[5]=524288;
  fa.s[6]=w2;  fa.d[6]=W2B; fa.n[6]=524288;
  fa.s[7]=rel; fa.d[7]=RELB;fa.n[7]=32768;
  f2b8_kernel<<<dim3(512,8), 256, 0, stream>>>(fa);
  tab_kernel<<<8, 256, 0, stream>>>(TAB);

  // conv block: out = x + pw(silu(dwconv(ln1(x))))
  ln_kernel<<<BS_, 128, 0, stream>>>(x, ln1g, ln1b, XN);
  dwconv_kernel<<<2048, 256, 0, stream>>>(XN, dww, dwb, DWS);
  gemm128_kernel<false,true,true,false><<<dim3(8,64), 256, 0, stream>>>(
      DWS, WPW, pwb, x, out, nullptr, BS_, 512, 512);

  // attention block
  ln_kernel<<<BS_, 128, 0, stream>>>(out, ln2g, ln2b, XN);
  gemm128_kernel<false,false,false,true><<<dim3(8,64), 256, 0, stream>>>(
      XN, WQ, qb, nullptr, nullptr, Q,   BS_, 512, 512);
  gemm128_kernel<false,false,false,true><<<dim3(8,64), 256, 0, stream>>>(
      XN, WK, kb, nullptr, nullptr, Kb_, BS_, 512, 512);
  gemm128_kernel<false,false,false,true><<<dim3(8,64), 256, 0, stream>>>(
      XN, WV, vb, nullptr, nullptr, V,   BS_, 512, 512);
  gemm_kernel<false,false,false,true><<<dim3(8,1), 256, 0, stream>>>(
      RELB, WK, kb, nullptr, nullptr, POSK, 64, 512, 512);
  gemm_kernel<false,false,false,true><<<dim3(8,1), 256, 0, stream>>>(
      RELB, WQ, qb, nullptr, nullptr, POSQ, 64, 512, 512);
  posbias_kernel<<<dim3(128,8), 256, 0, stream>>>(Q, Kb_, POSK, POSQ, C2P, P2C);
  vtrans_kernel<<<dim3(16,8,8), 256, 0, stream>>>(V, VT);
  flash_kernel<<<dim3(16,8,8), 256, 0, stream>>>(Q, Kb_, VT, C2P, P2C, TAB, CTX);
  gemm128_kernel<false,true,true,false><<<dim3(8,64), 256, 0, stream>>>(
      CTX, WO, ob, out, out, nullptr, BS_, 512, 512);

  // FFN block: out += w2 @ silu(w1 @ ln3(out))
  ln_kernel<<<BS_, 128, 0, stream>>>(out, ln3g, ln3b, XN);
  gemm128_kernel<true,false,false,true><<<dim3(16,64), 256, 0, stream>>>(
      XN, W1B, b1, nullptr, nullptr, FFH, BS_, 1024, 512);
  gemm128_kernel<false,true,true,false><<<dim3(8,64), 256, 0, stream>>>(
      FFH, W2B, b2, out, out, nullptr, BS_, 512, 1024);
}

// Round 4
// 385.834 us; speedup vs baseline: 1.3336x; 1.3336x over previous
//
#include <hip/hip_runtime.h>
#include <hip/hip_bf16.h>
#include <math.h>

// MEGConformerLayer: conv block + DeBERTa-v2 attention + FFN, all bf16 MFMA.
// B=8 S=1024 D=512 H=8 DH=64 K=3 FF=1024 BUCKETS=32 SPAN=32
// R4: flash v4 — coalesced LDS staging (R2) + pre-transposed VT + gather
// fast-path + pp_lds union buffer (R3 lessons). GEMMs unchanged from R3.

#define B_  8
#define S_  1024
#define D_  512
#define H_  8
#define DH_ 64
#define FF_ 1024
#define BS_ (B_*S_)   // 8192

typedef __attribute__((ext_vector_type(8))) short  short8;
typedef __attribute__((ext_vector_type(4))) short  short4v;
typedef __attribute__((ext_vector_type(4))) float  f32x4;
typedef __attribute__((ext_vector_type(4))) int    int4v;

static __device__ __forceinline__ float b2f(short u){
  union { int i; float f; } cv; cv.i = ((int)(unsigned short)u) << 16; return cv.f;
}
static __device__ __forceinline__ short f2b(float f){
  union { float f; unsigned u; } cv; cv.f = f;
  unsigned r = cv.u + 0x7FFFu + ((cv.u >> 16) & 1u);  // RNE
  return (short)(r >> 16);
}
static __device__ __forceinline__ float silu_f(float x){
  return x / (1.f + __expf(-x));
}
static __device__ __forceinline__ f32x4 mfma16(short8 a, short8 b, f32x4 c){
  return __builtin_amdgcn_mfma_f32_16x16x32_bf16(a, b, c, 0, 0, 0);
}

// ---------------- fused fp32 -> bf16 weight convert (8 segments, 1 launch) ----------------
struct F2B8 { const float* s[8]; short* d[8]; int n[8]; };
__global__ __launch_bounds__(256) void f2b8_kernel(F2B8 a){
  int seg = blockIdx.y;
  int i = (blockIdx.x*256 + threadIdx.x)*4;
  if (i >= a.n[seg]) return;
  float4 v = *(const float4*)(a.s[seg] + i);
  short4v o; o.x = f2b(v.x); o.y = f2b(v.y); o.z = f2b(v.z); o.w = f2b(v.w);
  *(short4v*)(a.d[seg] + i) = o;
}

// ---------------- DeBERTa log-bucket index table: delta=i-j in [-1023,1024] ----------------
__global__ __launch_bounds__(256) void tab_kernel(signed char* __restrict__ tab){
  int t = blockIdx.x*256 + threadIdx.x;
  if (t >= 2048) return;
  int d = t - 1023;
  int ad = d < 0 ? -d : d;
  int bkt;
  if (ad <= 16) bkt = d;
  else {
    const float inv_log = 15.f / logf(7.9375f);   // (mid-1)/log((MAX_REL-1)/mid)
    float lp = ceilf(logf((float)ad * (1.f/16.f)) * inv_log) + 16.f;
    int ilp = (int)lp;
    bkt = (d > 0) ? ilp : -ilp;
  }
  int idx = bkt + 32;
  idx = idx < 0 ? 0 : (idx > 63 ? 63 : idx);
  tab[t] = (signed char)idx;
}

// ---------------- LayerNorm (rows of 512), fp32 in -> bf16 out ----------------
__global__ __launch_bounds__(128) void ln_kernel(const float* __restrict__ x,
                                                 const float* __restrict__ g,
                                                 const float* __restrict__ bb,
                                                 short* __restrict__ out){
  int row = blockIdx.x;
  int tid = threadIdx.x;               // 128 threads * float4 = 512
  float4 v = ((const float4*)(x + (size_t)row*D_))[tid];
  float s  = v.x + v.y + v.z + v.w;
  float ss = v.x*v.x + v.y*v.y + v.z*v.z + v.w*v.w;
  #pragma unroll
  for (int off = 32; off; off >>= 1){ s += __shfl_down(s, off); ss += __shfl_down(ss, off); }
  __shared__ float red[4];
  if ((tid & 63) == 0){ red[tid>>6] = s; red[2 + (tid>>6)] = ss; }
  __syncthreads();
  float S  = red[0] + red[1];
  float SS = red[2] + red[3];
  float m   = S * (1.f/D_);
  float var = SS * (1.f/D_) - m*m;
  float rs  = rsqrtf(var + 1e-5f);
  float4 gv = ((const float4*)g)[tid];
  float4 bv = ((const float4*)bb)[tid];
  short4v o;
  o.x = f2b((v.x - m)*rs*gv.x + bv.x);
  o.y = f2b((v.y - m)*rs*gv.y + bv.y);
  o.z = f2b((v.z - m)*rs*gv.z + bv.z);
  o.w = f2b((v.w - m)*rs*gv.w + bv.w);
  *(short4v*)(out + (size_t)row*D_ + tid*4) = o;
}

// ---------------- depthwise conv (K=3, pad 1, per-seq) + SiLU, bf16->bf16 ----------------
__global__ __launch_bounds__(256) void dwconv_kernel(const short* __restrict__ xn,
                                                     const float* __restrict__ w,   // [D,1,3]
                                                     const float* __restrict__ bias,
                                                     short* __restrict__ out){
  int idx = blockIdx.x*256 + threadIdx.x;   // BS_*64 threads, 8 channels each
  int bs  = idx >> 6;
  int d8  = (idx & 63) << 3;
  int s   = bs & (S_-1);
  const short* base = xn + (size_t)bs*D_ + d8;
  short8 z = {};
  short8 xm = (s > 0)     ? *(const short8*)(base - D_) : z;
  short8 xc =               *(const short8*)(base);
  short8 xp = (s < S_-1)  ? *(const short8*)(base + D_) : z;
  short8 o;
  #pragma unroll
  for (int i = 0; i < 8; i++){
    int d = d8 + i;
    float acc = bias[d] + b2f(xm[i])*w[d*3+0] + b2f(xc[i])*w[d*3+1] + b2f(xp[i])*w[d*3+2];
    o[i] = f2b(silu_f(acc));
  }
  *(short8*)(out + (size_t)bs*D_ + d8) = o;
}

// ---------------- GEMM 128Mx64N tile, BK=64, 4 waves (2x2), each 64Mx32N ----------------
template<bool SILU, bool RES, bool OF32, bool OBF>
__global__ __launch_bounds__(256) void gemm128_kernel(const short* __restrict__ A,
                                                      const short* __restrict__ W,
                                                      const float* __restrict__ bias,
                                                      const float* res,
                                                      float* of32,
                                                      short* __restrict__ obf,
                                                      int M, int N, int K){
  __shared__ short a_lds[128][72];
  __shared__ short b_lds[64][72];
  int tid = threadIdx.x;
  int w = tid >> 6, lane = tid & 63, quad = lane >> 4, l16 = lane & 15;
  int wm = (w >> 1) * 64, wn = (w & 1) * 32;
  int m0 = blockIdx.y * 128, n0 = blockIdx.x * 64;
  f32x4 acc[4][2] = {};
  for (int kk = 0; kk < K; kk += 64){
    #pragma unroll
    for (int i = 0; i < 4; i++){               // A tile: 128x64 = 1024 chunks
      int c = i*256 + tid;
      int r = c >> 3, cc = (c & 7) * 8;
      *(int4v*)&a_lds[r][cc] = *(const int4v*)(A + (size_t)(m0+r)*K + kk + cc);
    }
    #pragma unroll
    for (int i = 0; i < 2; i++){               // B tile: 64x64 = 512 chunks
      int c = i*256 + tid;
      int r = c >> 3, cc = (c & 7) * 8;
      *(int4v*)&b_lds[r][cc] = *(const int4v*)(W + (size_t)(n0+r)*K + kk + cc);
    }
    __syncthreads();
    #pragma unroll
    for (int ks = 0; ks < 2; ks++){
      short8 b0 = *(const short8*)&b_lds[wn      + l16][ks*32 + quad*8];
      short8 b1 = *(const short8*)&b_lds[wn + 16 + l16][ks*32 + quad*8];
      #pragma unroll
      for (int mt = 0; mt < 4; mt++){
        short8 a = *(const short8*)&a_lds[wm + mt*16 + l16][ks*32 + quad*8];
        acc[mt][0] = mfma16(a, b0, acc[mt][0]);
        acc[mt][1] = mfma16(a, b1, acc[mt][1]);
      }
    }
    __syncthreads();
  }
  #pragma unroll
  for (int mt = 0; mt < 4; mt++)
    #pragma unroll
    for (int nt = 0; nt < 2; nt++)
      #pragma unroll
      for (int r = 0; r < 4; r++){
        int row = m0 + wm + mt*16 + quad*4 + r;
        int col = n0 + wn + nt*16 + l16;
        float val = acc[mt][nt][r] + bias[col];
        if (SILU) val = silu_f(val);
        if (RES)  val += res[(size_t)row*N + col];
        if (OF32) of32[(size_t)row*N + col] = val;
        if (OBF)  obf[(size_t)row*N + col] = f2b(val);
      }
}

// ---------------- GEMM 64x64 (for the two tiny M=64 pos-projection gemms) ----------------
template<bool SILU, bool RES, bool OF32, bool OBF>
__global__ __launch_bounds__(256) void gemm_kernel(const short* __restrict__ A,
                                                   const short* __restrict__ W,
                                                   const float* __restrict__ bias,
                                                   const float* res,
                                                   float* of32,
                                                   short* __restrict__ obf,
                                                   int M, int N, int K){
  __shared__ short a_lds[64][72];
  __shared__ short b_lds[64][72];
  int tid = threadIdx.x;
  int w = tid >> 6, lane = tid & 63, quad = lane >> 4, l16 = lane & 15;
  int wm = (w >> 1) * 32, wn = (w & 1) * 32;
  int m0 = blockIdx.y * 64, n0 = blockIdx.x * 64;
  int r0 = tid >> 3, c0 = (tid & 7) * 8;
  int r1 = r0 + 32;
  f32x4 acc[2][2] = {};
  for (int kk = 0; kk < K; kk += 64){
    *(int4v*)&a_lds[r0][c0] = *(const int4v*)(A + (size_t)(m0+r0)*K + kk + c0);
    *(int4v*)&a_lds[r1][c0] = *(const int4v*)(A + (size_t)(m0+r1)*K + kk + c0);
    *(int4v*)&b_lds[r0][c0] = *(const int4v*)(W + (size_t)(n0+r0)*K + kk + c0);
    *(int4v*)&b_lds[r1][c0] = *(const int4v*)(W + (size_t)(n0+r1)*K + kk + c0);
    __syncthreads();
    #pragma unroll
    for (int ks = 0; ks < 2; ks++){
      short8 a0 = *(const short8*)&a_lds[wm      + l16][ks*32 + quad*8];
      short8 a1 = *(const short8*)&a_lds[wm + 16 + l16][ks*32 + quad*8];
      short8 b0 = *(const short8*)&b_lds[wn      + l16][ks*32 + quad*8];
      short8 b1 = *(const short8*)&b_lds[wn + 16 + l16][ks*32 + quad*8];
      acc[0][0] = mfma16(a0, b0, acc[0][0]);
      acc[0][1] = mfma16(a0, b1, acc[0][1]);
      acc[1][0] = mfma16(a1, b0, acc[1][0]);
      acc[1][1] = mfma16(a1, b1, acc[1][1]);
    }
    __syncthreads();
  }
  #pragma unroll
  for (int mt = 0; mt < 2; mt++)
    #pragma unroll
    for (int nt = 0; nt < 2; nt++)
      #pragma unroll
      for (int r = 0; r < 4; r++){
        int row = m0 + wm + mt*16 + quad*4 + r;
        int col = n0 + wn + nt*16 + l16;
        float val = acc[mt][nt][r] + bias[col];
        if (SILU) val = silu_f(val);
        if (RES)  val += res[(size_t)row*N + col];
        if (OF32) of32[(size_t)row*N + col] = val;
        if (OBF)  obf[(size_t)row*N + col] = f2b(val);
      }
}

// ---------------- c2p/p2c position-bias batched GEMM ----------------
__global__ __launch_bounds__(256) void posbias_kernel(const short* __restrict__ q,
                                                      const short* __restrict__ k,
                                                      const short* __restrict__ posk,
                                                      const short* __restrict__ posq,
                                                      short* __restrict__ c2p,
                                                      short* __restrict__ p2c){
  int bsT = blockIdx.x;          // 128 tiles of 64 rows
  int h   = blockIdx.y;
  int tid = threadIdx.x, w = tid >> 6, lane = tid & 63, quad = lane >> 4, l16 = lane & 15;
  int row_a = bsT*64 + w*16 + l16;
  f32x4 accc[4] = {}, accp[4] = {};
  #pragma unroll
  for (int ks = 0; ks < 2; ks++){
    short8 aq = *(const short8*)(q + (size_t)row_a*D_ + h*DH_ + ks*32 + quad*8);
    short8 ak = *(const short8*)(k + (size_t)row_a*D_ + h*DH_ + ks*32 + quad*8);
    #pragma unroll
    for (int nt = 0; nt < 4; nt++){
      short8 bk = *(const short8*)(posk + (size_t)(nt*16+l16)*D_ + h*DH_ + ks*32 + quad*8);
      short8 bq = *(const short8*)(posq + (size_t)(nt*16+l16)*D_ + h*DH_ + ks*32 + quad*8);
      accc[nt] = mfma16(aq, bk, accc[nt]);
      accp[nt] = mfma16(ak, bq, accp[nt]);
    }
  }
  #pragma unroll
  for (int nt = 0; nt < 4; nt++)
    #pragma unroll
    for (int r = 0; r < 4; r++){
      int row = bsT*64 + w*16 + quad*4 + r;
      int col = h*DH_ + nt*16 + l16;
      c2p[(size_t)row*D_ + col] = f2b(accc[nt][r]);
      p2c[(size_t)row*D_ + col] = f2b(accp[nt][r]);
    }
}

// ---------------- V -> VT[B,H,DH,S] pre-transpose (65-pad: 2-way conflicts = free) ------
__global__ __launch_bounds__(256) void vtrans_kernel(const short* __restrict__ v,
                                                     short* __restrict__ vt){
  __shared__ short t_lds[64][65];
  int st = blockIdx.x, h = blockIdx.y, b = blockIdx.z;
  int s0 = st*64;
  int tid = threadIdx.x;
  #pragma unroll
  for (int i = 0; i < 2; i++){
    int c = i*256 + tid;
    int s = c >> 3, d8 = (c & 7) * 8;
    short8 vv = *(const short8*)(v + (size_t)(b*S_ + s0 + s)*D_ + h*DH_ + d8);
    #pragma unroll
    for (int jj = 0; jj < 8; jj++) t_lds[d8+jj][s] = vv[jj];
  }
  __syncthreads();
  #pragma unroll
  for (int i = 0; i < 2; i++){
    int c = i*256 + tid;
    int d = c >> 3, s8 = (c & 7) * 8;
    short8 o;
    #pragma unroll
    for (int jj = 0; jj < 8; jj++) o[jj] = t_lds[d][s8+jj];
    *(short8*)(vt + ((size_t)(b*H_ + h)*DH_ + d)*S_ + s0 + s8) = o;
  }
}

// ---------------- flash attention v4: coalesced LDS staging + gather fast path ----------
// block = (i-tile 64, h, b); 4 waves x 16 Q rows; online softmax over 16 j-tiles.
// K/VT/p2c tiles staged via coalesced loads + vector ds_writes; pp_lds doubles
// as p2c-tile (gather phase) and P-matrix (PV phase), split by a barrier.
__global__ __launch_bounds__(256, 4) void flash_kernel(const short* __restrict__ q,
                                                       const short* __restrict__ k,
                                                       const short* __restrict__ VT,
                                                       const short* __restrict__ c2p,
                                                       const short* __restrict__ p2c,
                                                       const signed char* __restrict__ TAB,
                                                       short* __restrict__ ctx){
  __shared__ short k_lds[64][72];
  __shared__ short v_lds[64][72];     // VT tile: [d][s_local]
  __shared__ short c2p_lds[64][72];
  __shared__ short pp_lds[64][72];    // p2c tile, then P matrix
  __shared__ signed char tab[2048];

  int it = blockIdx.x, h = blockIdx.y, b = blockIdx.z;
  int i0 = it * 64;
  int tid = threadIdx.x, w = tid >> 6, lane = tid & 63, quad = lane >> 4, l16 = lane & 15;
  const float scale = 0.07216878364f;   // 1/sqrt(DH*3)

  ((unsigned long long*)tab)[tid] = ((const unsigned long long*)TAB)[tid];  // 2048 B
  #pragma unroll
  for (int i = 0; i < 2; i++){
    int c = i*256 + tid;
    int r = c >> 3, cc = (c & 7) * 8;
    *(int4v*)&c2p_lds[r][cc] = *(const int4v*)(c2p + (size_t)(b*S_ + i0 + r)*D_ + h*DH_ + cc);
  }
  short8 qf0, qf1;
  {
    size_t row = (size_t)(b*S_ + i0 + w*16 + l16);
    qf0 = *(const short8*)(q + row*D_ + h*DH_ +      quad*8);
    qf1 = *(const short8*)(q + row*D_ + h*DH_ + 32 + quad*8);
  }
  __syncthreads();

  float cpos[4], cneg[4];
  #pragma unroll
  for (int r = 0; r < 4; r++){
    int iloc = w*16 + quad*4 + r;
    cpos[r] = b2f(c2p_lds[iloc][63]);   // saturated idx, i-j >= 129
    cneg[r] = b2f(c2p_lds[iloc][0]);    // saturated idx, i-j <= -129
  }
  f32x4 o_acc[4] = {};
  float mrow[4] = {-INFINITY, -INFINITY, -INFINITY, -INFINITY};
  float lrow[4] = {};
  const short* Kbase  = k   + (size_t)(b*S_)*D_ + h*DH_;
  const short* VTbase = VT  + (size_t)(b*H_ + h)*DH_*S_;
  const short* Pbase  = p2c + (size_t)(b*S_)*D_ + h*DH_;

  int st_r = tid >> 3, st_c = (tid & 7) * 8;   // staging coords (rows 0..31)

  for (int jt = 0; jt < 16; jt++){
    int j0 = jt * 64;
    bool near = (jt >= it-2 && jt <= it+2);
    // ---- stage K, VT, p2c tiles (coalesced 128B row-segments) ----
    #pragma unroll
    for (int i = 0; i < 2; i++){
      int r = st_r + i*32;
      size_t grow = (size_t)(b*S_ + j0 + r);
      *(int4v*)&k_lds[r][st_c]  = *(const int4v*)(Kbase + (size_t)(j0 + r)*D_ + st_c);
      *(int4v*)&v_lds[r][st_c]  = *(const int4v*)(VTbase + (size_t)r*S_ + j0 + st_c);
      *(int4v*)&pp_lds[r][st_c] = *(const int4v*)(Pbase + (size_t)(j0 + r)*D_ + st_c);
      (void)grow;
    }
    __syncthreads();

    // ---- S = Q K^T (per wave: 16 rows x 64 cols) ----
    f32x4 sfr[4];
    #pragma unroll
    for (int nt = 0; nt < 4; nt++){
      f32x4 a = {};
      a = mfma16(qf0, *(const short8*)&k_lds[nt*16+l16][     quad*8], a);
      a = mfma16(qf1, *(const short8*)&k_lds[nt*16+l16][32 + quad*8], a);
      sfr[nt] = a;
    }
    // ---- add (c2p + p2c) bias, scale ----
    float sval[4][4];
    if (near){
      #pragma unroll
      for (int nt = 0; nt < 4; nt++){
        int jloc = nt*16 + l16;
        #pragma unroll
        for (int r = 0; r < 4; r++){
          int iloc = w*16 + quad*4 + r;
          int idx  = tab[(i0 + iloc) - (j0 + jloc) + 1023];
          sval[nt][r] = (sfr[nt][r] + b2f(c2p_lds[iloc][idx]) + b2f(pp_lds[jloc][idx])) * scale;
        }
      }
    } else {
      int cidx = (jt < it) ? 63 : 0;
      const float* cP = (jt < it) ? cpos : cneg;
      #pragma unroll
      for (int nt = 0; nt < 4; nt++){
        float pv = b2f(pp_lds[nt*16 + l16][cidx]);
        #pragma unroll
        for (int r = 0; r < 4; r++)
          sval[nt][r] = (sfr[nt][r] + cP[r] + pv) * scale;
      }
    }
    // ---- online softmax (rows in 16-lane groups) ----
    float mnew[4], alpha[4], lsum[4];
    #pragma unroll
    for (int r = 0; r < 4; r++){
      float mx = fmaxf(fmaxf(sval[0][r], sval[1][r]), fmaxf(sval[2][r], sval[3][r]));
      #pragma unroll
      for (int off = 8; off; off >>= 1) mx = fmaxf(mx, __shfl_xor(mx, off));
      mnew[r]  = fmaxf(mrow[r], mx);
      alpha[r] = __expf(mrow[r] - mnew[r]);
      lsum[r]  = 0.f;
    }
    #pragma unroll
    for (int nt = 0; nt < 4; nt++)
      #pragma unroll
      for (int r = 0; r < 4; r++){
        float p = __expf(sval[nt][r] - mnew[r]);
        sval[nt][r] = p;
        lsum[r] += p;
      }
    #pragma unroll
    for (int r = 0; r < 4; r++){
      #pragma unroll
      for (int off = 8; off; off >>= 1) lsum[r] += __shfl_xor(lsum[r], off);
      lrow[r] = lrow[r]*alpha[r] + lsum[r];
      mrow[r] = mnew[r];
    }
    __syncthreads();   // all waves done reading pp_lds (p2c) before P overwrite

    // ---- P: C-layout -> A-layout via wave-private pp_lds band ----
    #pragma unroll
    for (int nt = 0; nt < 4; nt++)
      #pragma unroll
      for (int r = 0; r < 4; r++)
        pp_lds[w*16 + quad*4 + r][nt*16 + l16] = f2b(sval[nt][r]);
    #pragma unroll
    for (int nt = 0; nt < 4; nt++)
      #pragma unroll
      for (int r = 0; r < 4; r++) o_acc[nt][r] *= alpha[r];
    short8 pf0 = *(const short8*)&pp_lds[w*16 + l16][     quad*8];
    short8 pf1 = *(const short8*)&pp_lds[w*16 + l16][32 + quad*8];
    // ---- O += P V ----
    #pragma unroll
    for (int nt = 0; nt < 4; nt++){
      o_acc[nt] = mfma16(pf0, *(const short8*)&v_lds[nt*16+l16][     quad*8], o_acc[nt]);
      o_acc[nt] = mfma16(pf1, *(const short8*)&v_lds[nt*16+l16][32 + quad*8], o_acc[nt]);
    }
    __syncthreads();   // protect k/v/pp before next tile's staging
  }
  #pragma unroll
  for (int nt = 0; nt < 4; nt++)
    #pragma unroll
    for (int r = 0; r < 4; r++){
      size_t row = (size_t)(b*S_ + i0 + w*16 + quad*4 + r);
      ctx[row*D_ + h*DH_ + nt*16 + l16] = f2b(o_acc[nt][r] / lrow[r]);
    }
}

// ---------------- workspace layout (bytes) — high-water 55,248,896 (~52.7 MB) ----------------
// Aliases: DWS = C2P span (dead before posbias); VT = XN span (XN dead after
// q/k/v gemms, rewritten by ln3 after flash); CTX = V span (V dead after
// vtrans); FFH = Q..K span (dead after flash); fp32 residual chain in d_out.
static const size_t OFF_XN   = 0;           // bf16 8192x512  (alias: VT)
static const size_t OFF_Q    = 8388608;     // bf16 8192x512  (alias: FFH lo)
static const size_t OFF_K    = 16777216;    // bf16 8192x512  (alias: FFH hi)
static const size_t OFF_V    = 25165824;    // bf16 8192x512  (alias: CTX)
static const size_t OFF_C2P  = 33554432;    // bf16 8192x512  (alias: DWS)
static const size_t OFF_P2C  = 41943040;    // bf16 8192x512
static const size_t OFF_WPW  = 50331648;    // bf16 512x512
static const size_t OFF_WQ   = 50855936;
static const size_t OFF_WK   = 51380224;
static const size_t OFF_WV   = 51904512;
static const size_t OFF_WO   = 52428800;
static const size_t OFF_W1   = 52953088;    // bf16 1024x512
static const size_t OFF_W2   = 54001664;    // bf16 512x1024
static const size_t OFF_REL  = 55050240;    // bf16 64x512
static const size_t OFF_POSK = 55115776;    // bf16 64x512
static const size_t OFF_POSQ = 55181312;    // bf16 64x512
static const size_t OFF_TAB  = 55246848;    // int8 2048

extern "C" void kernel_launch(void* const* d_in, const int* in_sizes, int n_in,
                              void* d_out, int out_size, void* d_ws, size_t ws_size,
                              hipStream_t stream){
  const float* x    = (const float*)d_in[0];
  const float* ln1g = (const float*)d_in[1];
  const float* ln1b = (const float*)d_in[2];
  const float* dww  = (const float*)d_in[3];
  const float* dwb  = (const float*)d_in[4];
  const float* pww  = (const float*)d_in[5];
  const float* pwb  = (const float*)d_in[6];
  const float* ln2g = (const float*)d_in[7];
  const float* ln2b = (const float*)d_in[8];
  const float* qw   = (const float*)d_in[9];
  const float* qb   = (const float*)d_in[10];
  const float* kw   = (const float*)d_in[11];
  const float* kb   = (const float*)d_in[12];
  const float* vw   = (const float*)d_in[13];
  const float* vb   = (const float*)d_in[14];
  const float* ow   = (const float*)d_in[15];
  const float* ob   = (const float*)d_in[16];
  const float* rel  = (const float*)d_in[17];
  const float* ln3g = (const float*)d_in[18];
  const float* ln3b = (const float*)d_in[19];
  const float* w1   = (const float*)d_in[20];
  const float* b1   = (const float*)d_in[21];
  const float* w2   = (const float*)d_in[22];
  const float* b2   = (const float*)d_in[23];
  float* out = (float*)d_out;
  char* ws = (char*)d_ws;

  short* XN   = (short*)(ws + OFF_XN);
  short* Q    = (short*)(ws + OFF_Q);
  short* Kb_  = (short*)(ws + OFF_K);
  short* V    = (short*)(ws + OFF_V);
  short* C2P  = (short*)(ws + OFF_C2P);
  short* P2C  = (short*)(ws + OFF_P2C);
  short* WPW  = (short*)(ws + OFF_WPW);
  short* WQ   = (short*)(ws + OFF_WQ);
  short* WK   = (short*)(ws + OFF_WK);
  short* WV   = (short*)(ws + OFF_WV);
  short* WO   = (short*)(ws + OFF_WO);
  short* W1B  = (short*)(ws + OFF_W1);
  short* W2B  = (short*)(ws + OFF_W2);
  short* RELB = (short*)(ws + OFF_REL);
  short* POSK = (short*)(ws + OFF_POSK);
  short* POSQ = (short*)(ws + OFF_POSQ);
  signed char* TAB = (signed char*)(ws + OFF_TAB);
  short* DWS  = C2P;     // alias
  short* VT   = XN;      // alias
  short* CTX  = V;       // alias
  short* FFH  = Q;       // alias (16 MB over Q+K)

  // fused weight conversions + bucket table
  F2B8 fa;
  fa.s[0]=pww; fa.d[0]=WPW; fa.n[0]=262144;
  fa.s[1]=qw;  fa.d[1]=WQ;  fa.n[1]=262144;
  fa.s[2]=kw;  fa.d[2]=WK;  fa.n[2]=262144;
  fa.s[3]=vw;  fa.d[3]=WV;  fa.n[3]=262144;
  fa.s[4]=ow;  fa.d[4]=WO;  fa.n[4]=262144;
  fa.s[5]=w1;  fa.d[5]=W1B; fa.n[5]=524288;
  fa.s[6]=w2;  fa.d[6]=W2B; fa.n[6]=524288;
  fa.s[7]=rel; fa.d[7]=RELB;fa.n[7]=32768;
  f2b8_kernel<<<dim3(512,8), 256, 0, stream>>>(fa);
  tab_kernel<<<8, 256, 0, stream>>>(TAB);

  // conv block: out = x + pw(silu(dwconv(ln1(x))))
  ln_kernel<<<BS_, 128, 0, stream>>>(x, ln1g, ln1b, XN);
  dwconv_kernel<<<2048, 256, 0, stream>>>(XN, dww, dwb, DWS);
  gemm128_kernel<false,true,true,false><<<dim3(8,64), 256, 0, stream>>>(
      DWS, WPW, pwb, x, out, nullptr, BS_, 512, 512);

  // attention block
  ln_kernel<<<BS_, 128, 0, stream>>>(out, ln2g, ln2b, XN);
  gemm128_kernel<false,false,false,true><<<dim3(8,64), 256, 0, stream>>>(
      XN, WQ, qb, nullptr, nullptr, Q,   BS_, 512, 512);
  gemm128_kernel<false,false,false,true><<<dim3(8,64), 256, 0, stream>>>(
      XN, WK, kb, nullptr, nullptr, Kb_, BS_, 512, 512);
  gemm128_kernel<false,false,false,true><<<dim3(8,64), 256, 0, stream>>>(
      XN, WV, vb, nullptr, nullptr, V,   BS_, 512, 512);
  gemm_kernel<false,false,false,true><<<dim3(8,1), 256, 0, stream>>>(
      RELB, WK, kb, nullptr, nullptr, POSK, 64, 512, 512);
  gemm_kernel<false,false,false,true><<<dim3(8,1), 256, 0, stream>>>(
      RELB, WQ, qb, nullptr, nullptr, POSQ, 64, 512, 512);
  posbias_kernel<<<dim3(128,8), 256, 0, stream>>>(Q, Kb_, POSK, POSQ, C2P, P2C);
  vtrans_kernel<<<dim3(16,8,8), 256, 0, stream>>>(V, VT);
  flash_kernel<<<dim3(16,8,8), 256, 0, stream>>>(Q, Kb_, VT, C2P, P2C, TAB, CTX);
  gemm128_kernel<false,true,true,false><<<dim3(8,64), 256, 0, stream>>>(
      CTX, WO, ob, out, out, nullptr, BS_, 512, 512);

  // FFN block: out += w2 @ silu(w1 @ ln3(out))
  ln_kernel<<<BS_, 128, 0, stream>>>(out, ln3g, ln3b, XN);
  gemm128_kernel<true,false,false,true><<<dim3(16,64), 256, 0, stream>>>(
      XN, W1B, b1, nullptr, nullptr, FFH, BS_, 1024, 512);
  gemm128_kernel<false,true,true,false><<<dim3(8,64), 256, 0, stream>>>(
      FFH, W2B, b2, out, out, nullptr, BS_, 512, 1024);
}

// Round 5
// 350.504 us; speedup vs baseline: 1.4680x; 1.1008x over previous
//
#include <hip/hip_runtime.h>
#include <hip/hip_bf16.h>
#include <math.h>

// MEGConformerLayer: conv block + DeBERTa-v2 attention + FFN, all bf16 MFMA.
// B=8 S=1024 D=512 H=8 DH=64 K=3 FF=1024 BUCKETS=32 SPAN=32
// R5: gemms use global_load_lds(16B) + XOR-swizzled LDS (m97 ladder step);
//     QKV fused into one N=1536 gemm; flash drops online-max softmax
//     (scores provably tiny), scale folded into Q/POSQ, P-write stride 68.

#define B_  8
#define S_  1024
#define D_  512
#define H_  8
#define DH_ 64
#define FF_ 1024
#define BS_ (B_*S_)   // 8192
#define SCALE_ 0.07216878364f   // 1/sqrt(DH*3)

typedef __attribute__((ext_vector_type(8))) short  short8;
typedef __attribute__((ext_vector_type(4))) short  short4v;
typedef __attribute__((ext_vector_type(4))) float  f32x4;
typedef __attribute__((ext_vector_type(4))) int    int4v;

static __device__ __forceinline__ float b2f(short u){
  union { int i; float f; } cv; cv.i = ((int)(unsigned short)u) << 16; return cv.f;
}
static __device__ __forceinline__ short f2b(float f){
  union { float f; unsigned u; } cv; cv.f = f;
  unsigned r = cv.u + 0x7FFFu + ((cv.u >> 16) & 1u);  // RNE
  return (short)(r >> 16);
}
static __device__ __forceinline__ float silu_f(float x){
  return x / (1.f + __expf(-x));
}
static __device__ __forceinline__ f32x4 mfma16(short8 a, short8 b, f32x4 c){
  return __builtin_amdgcn_mfma_f32_16x16x32_bf16(a, b, c, 0, 0, 0);
}
// async global->LDS, 16B/lane; dest = wave-uniform base + lane*16
static __device__ __forceinline__ void gl16(const void* g, void* l){
  __builtin_amdgcn_global_load_lds((const __attribute__((address_space(1))) void*)g,
                                   (__attribute__((address_space(3))) void*)l, 16, 0, 0);
}

// ---------------- fused fp32 -> bf16 weight convert (8 segments, 1 launch) ----------------
struct F2B8 { const float* s[8]; short* d[8]; int n[8]; };
__global__ __launch_bounds__(256) void f2b8_kernel(F2B8 a){
  int seg = blockIdx.y;
  int i = (blockIdx.x*256 + threadIdx.x)*4;
  if (i >= a.n[seg]) return;
  float4 v = *(const float4*)(a.s[seg] + i);
  short4v o; o.x = f2b(v.x); o.y = f2b(v.y); o.z = f2b(v.z); o.w = f2b(v.w);
  *(short4v*)(a.d[seg] + i) = o;
}

// ---------------- DeBERTa log-bucket index table: delta=i-j in [-1023,1024] ----------------
__global__ __launch_bounds__(256) void tab_kernel(signed char* __restrict__ tab){
  int t = blockIdx.x*256 + threadIdx.x;
  if (t >= 2048) return;
  int d = t - 1023;
  int ad = d < 0 ? -d : d;
  int bkt;
  if (ad <= 16) bkt = d;
  else {
    const float inv_log = 15.f / logf(7.9375f);   // (mid-1)/log((MAX_REL-1)/mid)
    float lp = ceilf(logf((float)ad * (1.f/16.f)) * inv_log) + 16.f;
    int ilp = (int)lp;
    bkt = (d > 0) ? ilp : -ilp;
  }
  int idx = bkt + 32;
  idx = idx < 0 ? 0 : (idx > 63 ? 63 : idx);
  tab[t] = (signed char)idx;
}

// ---------------- LayerNorm (rows of 512), fp32 in -> bf16 out ----------------
__global__ __launch_bounds__(128) void ln_kernel(const float* __restrict__ x,
                                                 const float* __restrict__ g,
                                                 const float* __restrict__ bb,
                                                 short* __restrict__ out){
  int row = blockIdx.x;
  int tid = threadIdx.x;               // 128 threads * float4 = 512
  float4 v = ((const float4*)(x + (size_t)row*D_))[tid];
  float s  = v.x + v.y + v.z + v.w;
  float ss = v.x*v.x + v.y*v.y + v.z*v.z + v.w*v.w;
  #pragma unroll
  for (int off = 32; off; off >>= 1){ s += __shfl_down(s, off); ss += __shfl_down(ss, off); }
  __shared__ float red[4];
  if ((tid & 63) == 0){ red[tid>>6] = s; red[2 + (tid>>6)] = ss; }
  __syncthreads();
  float S  = red[0] + red[1];
  float SS = red[2] + red[3];
  float m   = S * (1.f/D_);
  float var = SS * (1.f/D_) - m*m;
  float rs  = rsqrtf(var + 1e-5f);
  float4 gv = ((const float4*)g)[tid];
  float4 bv = ((const float4*)bb)[tid];
  short4v o;
  o.x = f2b((v.x - m)*rs*gv.x + bv.x);
  o.y = f2b((v.y - m)*rs*gv.y + bv.y);
  o.z = f2b((v.z - m)*rs*gv.z + bv.z);
  o.w = f2b((v.w - m)*rs*gv.w + bv.w);
  *(short4v*)(out + (size_t)row*D_ + tid*4) = o;
}

// ---------------- depthwise conv (K=3, pad 1, per-seq) + SiLU, bf16->bf16 ----------------
__global__ __launch_bounds__(256) void dwconv_kernel(const short* __restrict__ xn,
                                                     const float* __restrict__ w,   // [D,1,3]
                                                     const float* __restrict__ bias,
                                                     short* __restrict__ out){
  int idx = blockIdx.x*256 + threadIdx.x;   // BS_*64 threads, 8 channels each
  int bs  = idx >> 6;
  int d8  = (idx & 63) << 3;
  int s   = bs & (S_-1);
  const short* base = xn + (size_t)bs*D_ + d8;
  short8 z = {};
  short8 xm = (s > 0)     ? *(const short8*)(base - D_) : z;
  short8 xc =               *(const short8*)(base);
  short8 xp = (s < S_-1)  ? *(const short8*)(base + D_) : z;
  short8 o;
  #pragma unroll
  for (int i = 0; i < 8; i++){
    int d = d8 + i;
    float acc = bias[d] + b2f(xm[i])*w[d*3+0] + b2f(xc[i])*w[d*3+1] + b2f(xp[i])*w[d*3+2];
    o[i] = f2b(silu_f(acc));
  }
  *(short8*)(out + (size_t)bs*D_ + d8) = o;
}

// ====== GEMM core with global_load_lds staging + XOR-swizzled unpadded LDS ======
// 128Mx64N tile, BK=64, 4 waves (2x2), each 64Mx32N. chunk c (16B) of row r
// stored at physical chunk c^(r&7) -> reads are 2-way-conflict-free.
#define GEMM_GL_CORE(AP, WP, KK)                                               \
  __shared__ short a_lds[128*64];                                              \
  __shared__ short b_lds[64*64];                                               \
  int tid = threadIdx.x;                                                       \
  int w = tid >> 6, lane = tid & 63, quad = lane >> 4, l16 = lane & 15;        \
  int wm = (w >> 1) * 64, wn = (w & 1) * 32;                                   \
  int m0 = blockIdx.y * 128, n0 = blockIdx.x * 64;                             \
  const short* aptr[4]; const short* bptr[2];                                  \
  _Pragma("unroll")                                                            \
  for (int i = 0; i < 4; i++){                                                 \
    int slot = i*256 + tid;                                                    \
    int r = slot >> 3, c = (slot & 7) ^ (r & 7);                               \
    aptr[i] = AP + (size_t)(m0 + r)*KK + c*8;                                  \
  }                                                                            \
  _Pragma("unroll")                                                            \
  for (int i = 0; i < 2; i++){                                                 \
    int slot = i*256 + tid;                                                    \
    int r = slot >> 3, c = (slot & 7) ^ (r & 7);                               \
    bptr[i] = WP + (size_t)(n0 + r)*KK + c*8;                                  \
  }                                                                            \
  f32x4 acc[4][2] = {};                                                        \
  int sw = l16 & 7;                                                            \
  for (int kk = 0; kk < KK; kk += 64){                                         \
    _Pragma("unroll")                                                          \
    for (int i = 0; i < 4; i++) gl16(aptr[i] + kk, &a_lds[(i*256 + w*64)*8]);  \
    _Pragma("unroll")                                                          \
    for (int i = 0; i < 2; i++) gl16(bptr[i] + kk, &b_lds[(i*256 + w*64)*8]);  \
    __syncthreads();                                                           \
    _Pragma("unroll")                                                          \
    for (int ks = 0; ks < 2; ks++){                                            \
      short8 b0 = *(const short8*)&b_lds[(wn      + l16)*64 + ((ks*4+quad)^sw)*8]; \
      short8 b1 = *(const short8*)&b_lds[(wn + 16 + l16)*64 + ((ks*4+quad)^sw)*8]; \
      _Pragma("unroll")                                                        \
      for (int mt = 0; mt < 4; mt++){                                          \
        short8 a = *(const short8*)&a_lds[(wm + mt*16 + l16)*64 + ((ks*4+quad)^sw)*8]; \
        acc[mt][0] = mfma16(a, b0, acc[mt][0]);                                \
        acc[mt][1] = mfma16(a, b1, acc[mt][1]);                                \
      }                                                                        \
    }                                                                          \
    __syncthreads();                                                           \
  }

template<bool SILU, bool RES, bool OF32, bool OBF>
__global__ __launch_bounds__(256) void gemm_gl(const short* __restrict__ A,
                                               const short* __restrict__ W,
                                               const float* __restrict__ bias,
                                               const float* res,
                                               float* of32,
                                               short* __restrict__ obf,
                                               int M, int N, int K){
  GEMM_GL_CORE(A, W, K)
  #pragma unroll
  for (int mt = 0; mt < 4; mt++)
    #pragma unroll
    for (int nt = 0; nt < 2; nt++)
      #pragma unroll
      for (int r = 0; r < 4; r++){
        int row = m0 + wm + mt*16 + quad*4 + r;
        int col = n0 + wn + nt*16 + l16;
        float val = acc[mt][nt][r] + bias[col];
        if (SILU) val = silu_f(val);
        if (RES)  val += res[(size_t)row*N + col];
        if (OF32) of32[(size_t)row*N + col] = val;
        if (OBF)  obf[(size_t)row*N + col] = f2b(val);
      }
}

// fused QKV projection: W = [WQ;WK;WV] (1536x512 contiguous), outputs split,
// Q pre-scaled by SCALE_ (folds attention scale into QK^T and c2p).
__global__ __launch_bounds__(256) void gemm_qkv(const short* __restrict__ A,
                                                const short* __restrict__ W,
                                                const float* __restrict__ qb,
                                                const float* __restrict__ kb,
                                                const float* __restrict__ vb,
                                                short* __restrict__ Qo,
                                                short* __restrict__ Ko,
                                                short* __restrict__ Vo,
                                                int M, int K){
  GEMM_GL_CORE(A, W, K)
  int colb = n0 + wn;
  int sel = colb >> 9;                       // uniform per (block, wn, nt) tile
  const float* bp = sel == 0 ? qb : (sel == 1 ? kb : vb);
  short* dp = sel == 0 ? Qo : (sel == 1 ? Ko : Vo);
  float mult = sel == 0 ? SCALE_ : 1.f;
  #pragma unroll
  for (int mt = 0; mt < 4; mt++)
    #pragma unroll
    for (int nt = 0; nt < 2; nt++)
      #pragma unroll
      for (int r = 0; r < 4; r++){
        int row = m0 + wm + mt*16 + quad*4 + r;
        int col = (colb + nt*16 + l16) & 511;
        float val = (acc[mt][nt][r] + bp[col]) * mult;
        dp[(size_t)row*D_ + col] = f2b(val);
      }
}

// ---------------- GEMM 64x64 (two tiny M=64 pos-projection gemms) ----------------
__global__ __launch_bounds__(256) void gemm_pos(const short* __restrict__ A,
                                                const short* __restrict__ W,
                                                const float* __restrict__ bias,
                                                short* __restrict__ obf,
                                                float mult, int N, int K){
  __shared__ short a_lds[64][72];
  __shared__ short b_lds[64][72];
  int tid = threadIdx.x;
  int w = tid >> 6, lane = tid & 63, quad = lane >> 4, l16 = lane & 15;
  int wm = (w >> 1) * 32, wn = (w & 1) * 32;
  int m0 = 0, n0 = blockIdx.x * 64;
  int r0 = tid >> 3, c0 = (tid & 7) * 8;
  int r1 = r0 + 32;
  f32x4 acc[2][2] = {};
  for (int kk = 0; kk < K; kk += 64){
    *(int4v*)&a_lds[r0][c0] = *(const int4v*)(A + (size_t)(m0+r0)*K + kk + c0);
    *(int4v*)&a_lds[r1][c0] = *(const int4v*)(A + (size_t)(m0+r1)*K + kk + c0);
    *(int4v*)&b_lds[r0][c0] = *(const int4v*)(W + (size_t)(n0+r0)*K + kk + c0);
    *(int4v*)&b_lds[r1][c0] = *(const int4v*)(W + (size_t)(n0+r1)*K + kk + c0);
    __syncthreads();
    #pragma unroll
    for (int ks = 0; ks < 2; ks++){
      short8 a0 = *(const short8*)&a_lds[wm      + l16][ks*32 + quad*8];
      short8 a1 = *(const short8*)&a_lds[wm + 16 + l16][ks*32 + quad*8];
      short8 b0 = *(const short8*)&b_lds[wn      + l16][ks*32 + quad*8];
      short8 b1 = *(const short8*)&b_lds[wn + 16 + l16][ks*32 + quad*8];
      acc[0][0] = mfma16(a0, b0, acc[0][0]);
      acc[0][1] = mfma16(a0, b1, acc[0][1]);
      acc[1][0] = mfma16(a1, b0, acc[1][0]);
      acc[1][1] = mfma16(a1, b1, acc[1][1]);
    }
    __syncthreads();
  }
  #pragma unroll
  for (int mt = 0; mt < 2; mt++)
    #pragma unroll
    for (int nt = 0; nt < 2; nt++)
      #pragma unroll
      for (int r = 0; r < 4; r++){
        int row = m0 + wm + mt*16 + quad*4 + r;
        int col = n0 + wn + nt*16 + l16;
        obf[(size_t)row*N + col] = f2b((acc[mt][nt][r] + bias[col]) * mult);
      }
}

// ---------------- c2p/p2c position-bias batched GEMM ----------------
// q pre-scaled -> c2p scaled; posq pre-scaled -> p2c scaled.
__global__ __launch_bounds__(256) void posbias_kernel(const short* __restrict__ q,
                                                      const short* __restrict__ k,
                                                      const short* __restrict__ posk,
                                                      const short* __restrict__ posq,
                                                      short* __restrict__ c2p,
                                                      short* __restrict__ p2c){
  int bsT = blockIdx.x;          // 128 tiles of 64 rows
  int h   = blockIdx.y;
  int tid = threadIdx.x, w = tid >> 6, lane = tid & 63, quad = lane >> 4, l16 = lane & 15;
  int row_a = bsT*64 + w*16 + l16;
  f32x4 accc[4] = {}, accp[4] = {};
  #pragma unroll
  for (int ks = 0; ks < 2; ks++){
    short8 aq = *(const short8*)(q + (size_t)row_a*D_ + h*DH_ + ks*32 + quad*8);
    short8 ak = *(const short8*)(k + (size_t)row_a*D_ + h*DH_ + ks*32 + quad*8);
    #pragma unroll
    for (int nt = 0; nt < 4; nt++){
      short8 bk = *(const short8*)(posk + (size_t)(nt*16+l16)*D_ + h*DH_ + ks*32 + quad*8);
      short8 bq = *(const short8*)(posq + (size_t)(nt*16+l16)*D_ + h*DH_ + ks*32 + quad*8);
      accc[nt] = mfma16(aq, bk, accc[nt]);
      accp[nt] = mfma16(ak, bq, accp[nt]);
    }
  }
  #pragma unroll
  for (int nt = 0; nt < 4; nt++)
    #pragma unroll
    for (int r = 0; r < 4; r++){
      int row = bsT*64 + w*16 + quad*4 + r;
      int col = h*DH_ + nt*16 + l16;
      c2p[(size_t)row*D_ + col] = f2b(accc[nt][r]);
      p2c[(size_t)row*D_ + col] = f2b(accp[nt][r]);
    }
}

// ---------------- V -> VT[B,H,DH,S] pre-transpose (65-pad: 2-way conflicts = free) ------
__global__ __launch_bounds__(256) void vtrans_kernel(const short* __restrict__ v,
                                                     short* __restrict__ vt){
  __shared__ short t_lds[64][65];
  int st = blockIdx.x, h = blockIdx.y, b = blockIdx.z;
  int s0 = st*64;
  int tid = threadIdx.x;
  #pragma unroll
  for (int i = 0; i < 2; i++){
    int c = i*256 + tid;
    int s = c >> 3, d8 = (c & 7) * 8;
    short8 vv = *(const short8*)(v + (size_t)(b*S_ + s0 + s)*D_ + h*DH_ + d8);
    #pragma unroll
    for (int jj = 0; jj < 8; jj++) t_lds[d8+jj][s] = vv[jj];
  }
  __syncthreads();
  #pragma unroll
  for (int i = 0; i < 2; i++){
    int c = i*256 + tid;
    int d = c >> 3, s8 = (c & 7) * 8;
    short8 o;
    #pragma unroll
    for (int jj = 0; jj < 8; jj++) o[jj] = t_lds[d][s8+jj];
    *(short8*)(vt + ((size_t)(b*H_ + h)*DH_ + d)*S_ + s0 + s8) = o;
  }
}

// ---------------- flash attention v5: no-max softmax (scores provably small) ------------
// Q pre-scaled; c2p/p2c pre-scaled. P = exp(s) directly; l accumulated as
// per-lane partials, one reduction at the end. pp stride 68 (write-conflict-free).
#define PPS 68
__global__ __launch_bounds__(256, 4) void flash_kernel(const short* __restrict__ q,
                                                       const short* __restrict__ k,
                                                       const short* __restrict__ VT,
                                                       const short* __restrict__ c2p,
                                                       const short* __restrict__ p2c,
                                                       const signed char* __restrict__ TAB,
                                                       short* __restrict__ ctx){
  __shared__ short k_lds[64][72];
  __shared__ short v_lds[64][72];     // VT tile: [d][s_local]
  __shared__ short c2p_lds[64][72];
  __shared__ short pp_lds[64][PPS];   // p2c tile, then P matrix
  __shared__ signed char tab[2048];

  int it = blockIdx.x, h = blockIdx.y, b = blockIdx.z;
  int i0 = it * 64;
  int tid = threadIdx.x, w = tid >> 6, lane = tid & 63, quad = lane >> 4, l16 = lane & 15;

  ((unsigned long long*)tab)[tid] = ((const unsigned long long*)TAB)[tid];  // 2048 B
  #pragma unroll
  for (int i = 0; i < 2; i++){
    int c = i*256 + tid;
    int r = c >> 3, cc = (c & 7) * 8;
    *(int4v*)&c2p_lds[r][cc] = *(const int4v*)(c2p + (size_t)(b*S_ + i0 + r)*D_ + h*DH_ + cc);
  }
  short8 qf0, qf1;
  {
    size_t row = (size_t)(b*S_ + i0 + w*16 + l16);
    qf0 = *(const short8*)(q + row*D_ + h*DH_ +      quad*8);
    qf1 = *(const short8*)(q + row*D_ + h*DH_ + 32 + quad*8);
  }
  __syncthreads();

  float cpos[4], cneg[4];
  #pragma unroll
  for (int r = 0; r < 4; r++){
    int iloc = w*16 + quad*4 + r;
    cpos[r] = b2f(c2p_lds[iloc][63]);   // saturated idx, i-j >= 129
    cneg[r] = b2f(c2p_lds[iloc][0]);    // saturated idx, i-j <= -129
  }
  f32x4 o_acc[4] = {};
  float lrow[4] = {};                    // per-lane partial sums
  const short* Kbase  = k   + (size_t)(b*S_)*D_ + h*DH_;
  const short* VTbase = VT  + (size_t)(b*H_ + h)*DH_*S_;
  const short* Pbase  = p2c + (size_t)(b*S_)*D_ + h*DH_;

  int st_r = tid >> 3, st_c = (tid & 7) * 8;   // staging coords (rows 0..31)

  for (int jt = 0; jt < 16; jt++){
    int j0 = jt * 64;
    bool near = (jt >= it-2 && jt <= it+2);
    // ---- stage K, VT, p2c tiles (coalesced 128B row-segments) ----
    #pragma unroll
    for (int i = 0; i < 2; i++){
      int r = st_r + i*32;
      *(int4v*)&k_lds[r][st_c]  = *(const int4v*)(Kbase + (size_t)(j0 + r)*D_ + st_c);
      *(int4v*)&v_lds[r][st_c]  = *(const int4v*)(VTbase + (size_t)r*S_ + j0 + st_c);
      *(int4v*)&pp_lds[r][st_c] = *(const int4v*)(Pbase + (size_t)(j0 + r)*D_ + st_c);
    }
    __syncthreads();

    // ---- S = Q K^T (per wave: 16 rows x 64 cols), already scaled ----
    f32x4 sfr[4];
    #pragma unroll
    for (int nt = 0; nt < 4; nt++){
      f32x4 a = {};
      a = mfma16(qf0, *(const short8*)&k_lds[nt*16+l16][     quad*8], a);
      a = mfma16(qf1, *(const short8*)&k_lds[nt*16+l16][32 + quad*8], a);
      sfr[nt] = a;
    }
    // ---- P = exp(S + c2p + p2c); accumulate per-lane l partials ----
    float pval[4][4];
    if (near){
      #pragma unroll
      for (int nt = 0; nt < 4; nt++){
        int jloc = nt*16 + l16;
        #pragma unroll
        for (int r = 0; r < 4; r++){
          int iloc = w*16 + quad*4 + r;
          int idx  = tab[(i0 + iloc) - (j0 + jloc) + 1023];
          float p = __expf(sfr[nt][r] + b2f(c2p_lds[iloc][idx]) + b2f(pp_lds[jloc][idx]));
          pval[nt][r] = p;
          lrow[r] += p;
        }
      }
    } else {
      int cidx = (jt < it) ? 63 : 0;
      const float* cP = (jt < it) ? cpos : cneg;
      #pragma unroll
      for (int nt = 0; nt < 4; nt++){
        float pv = b2f(pp_lds[nt*16 + l16][cidx]);
        #pragma unroll
        for (int r = 0; r < 4; r++){
          float p = __expf(sfr[nt][r] + cP[r] + pv);
          pval[nt][r] = p;
          lrow[r] += p;
        }
      }
    }
    __syncthreads();   // all waves done reading pp_lds (p2c) before P overwrite

    // ---- P: C-layout -> A-layout via wave-private pp_lds band ----
    #pragma unroll
    for (int nt = 0; nt < 4; nt++)
      #pragma unroll
      for (int r = 0; r < 4; r++)
        pp_lds[w*16 + quad*4 + r][nt*16 + l16] = f2b(pval[nt][r]);
    short8 pf0 = *(const short8*)&pp_lds[w*16 + l16][     quad*8];
    short8 pf1 = *(const short8*)&pp_lds[w*16 + l16][32 + quad*8];
    // ---- O += P V ----
    #pragma unroll
    for (int nt = 0; nt < 4; nt++){
      o_acc[nt] = mfma16(pf0, *(const short8*)&v_lds[nt*16+l16][     quad*8], o_acc[nt]);
      o_acc[nt] = mfma16(pf1, *(const short8*)&v_lds[nt*16+l16][32 + quad*8], o_acc[nt]);
    }
    __syncthreads();   // protect k/v/pp before next tile's staging
  }
  // final row-sum reduction over the 16 lanes of each quad group
  #pragma unroll
  for (int r = 0; r < 4; r++){
    #pragma unroll
    for (int off = 8; off; off >>= 1) lrow[r] += __shfl_xor(lrow[r], off);
  }
  #pragma unroll
  for (int nt = 0; nt < 4; nt++)
    #pragma unroll
    for (int r = 0; r < 4; r++){
      size_t row = (size_t)(b*S_ + i0 + w*16 + quad*4 + r);
      ctx[row*D_ + h*DH_ + nt*16 + l16] = f2b(o_acc[nt][r] / lrow[r]);
    }
}

// ---------------- workspace layout (bytes) — high-water 55,248,896 (~52.7 MB) ----------------
// Aliases: DWS = C2P span (dead before posbias); VT = XN span (XN dead after
// qkv gemm); CTX = V span (V dead after vtrans); FFH = Q..K span (dead after
// flash); fp32 residual chain lives in d_out (same-thread RMW in epilogues).
static const size_t OFF_XN   = 0;           // bf16 8192x512  (alias: VT)
static const size_t OFF_Q    = 8388608;     // bf16 8192x512  (alias: FFH lo)
static const size_t OFF_K    = 16777216;    // bf16 8192x512  (alias: FFH hi)
static const size_t OFF_V    = 25165824;    // bf16 8192x512  (alias: CTX)
static const size_t OFF_C2P  = 33554432;    // bf16 8192x512  (alias: DWS)
static const size_t OFF_P2C  = 41943040;    // bf16 8192x512
static const size_t OFF_WPW  = 50331648;    // bf16 512x512
static const size_t OFF_WQ   = 50855936;    // WQ/WK/WV contiguous = [1536,512]
static const size_t OFF_WK   = 51380224;
static const size_t OFF_WV   = 51904512;
static const size_t OFF_WO   = 52428800;
static const size_t OFF_W1   = 52953088;    // bf16 1024x512
static const size_t OFF_W2   = 54001664;    // bf16 512x1024
static const size_t OFF_REL  = 55050240;    // bf16 64x512
static const size_t OFF_POSK = 55115776;    // bf16 64x512
static const size_t OFF_POSQ = 55181312;    // bf16 64x512
static const size_t OFF_TAB  = 55246848;    // int8 2048

extern "C" void kernel_launch(void* const* d_in, const int* in_sizes, int n_in,
                              void* d_out, int out_size, void* d_ws, size_t ws_size,
                              hipStream_t stream){
  const float* x    = (const float*)d_in[0];
  const float* ln1g = (const float*)d_in[1];
  const float* ln1b = (const float*)d_in[2];
  const float* dww  = (const float*)d_in[3];
  const float* dwb  = (const float*)d_in[4];
  const float* pww  = (const float*)d_in[5];
  const float* pwb  = (const float*)d_in[6];
  const float* ln2g = (const float*)d_in[7];
  const float* ln2b = (const float*)d_in[8];
  const float* qw   = (const float*)d_in[9];
  const float* qb   = (const float*)d_in[10];
  const float* kw   = (const float*)d_in[11];
  const float* kb   = (const float*)d_in[12];
  const float* vw   = (const float*)d_in[13];
  const float* vb   = (const float*)d_in[14];
  const float* ow   = (const float*)d_in[15];
  const float* ob   = (const float*)d_in[16];
  const float* rel  = (const float*)d_in[17];
  const float* ln3g = (const float*)d_in[18];
  const float* ln3b = (const float*)d_in[19];
  const float* w1   = (const float*)d_in[20];
  const float* b1   = (const float*)d_in[21];
  const float* w2   = (const float*)d_in[22];
  const float* b2   = (const float*)d_in[23];
  float* out = (float*)d_out;
  char* ws = (char*)d_ws;

  short* XN   = (short*)(ws + OFF_XN);
  short* Q    = (short*)(ws + OFF_Q);
  short* Kb_  = (short*)(ws + OFF_K);
  short* V    = (short*)(ws + OFF_V);
  short* C2P  = (short*)(ws + OFF_C2P);
  short* P2C  = (short*)(ws + OFF_P2C);
  short* WPW  = (short*)(ws + OFF_WPW);
  short* WQ   = (short*)(ws + OFF_WQ);
  short* WK   = (short*)(ws + OFF_WK);
  short* WV   = (short*)(ws + OFF_WV);
  short* WO   = (short*)(ws + OFF_WO);
  short* W1B  = (short*)(ws + OFF_W1);
  short* W2B  = (short*)(ws + OFF_W2);
  short* RELB = (short*)(ws + OFF_REL);
  short* POSK = (short*)(ws + OFF_POSK);
  short* POSQ = (short*)(ws + OFF_POSQ);
  signed char* TAB = (signed char*)(ws + OFF_TAB);
  short* DWS  = C2P;     // alias
  short* VT   = XN;      // alias
  short* CTX  = V;       // alias
  short* FFH  = Q;       // alias (16 MB over Q+K)

  // fused weight conversions + bucket table
  F2B8 fa;
  fa.s[0]=pww; fa.d[0]=WPW; fa.n[0]=262144;
  fa.s[1]=qw;  fa.d[1]=WQ;  fa.n[1]=262144;
  fa.s[2]=kw;  fa.d[2]=WK;  fa.n[2]=262144;
  fa.s[3]=vw;  fa.d[3]=WV;  fa.n[3]=262144;
  fa.s[4]=ow;  fa.d[4]=WO;  fa.n[4]=262144;
  fa.s[5]=w1;  fa.d[5]=W1B; fa.n[5]=524288;
  fa.s[6]=w2;  fa.d[6]=W2B; fa.n[6]=524288;
  fa.s[7]=rel; fa.d[7]=RELB;fa.n[7]=32768;
  f2b8_kernel<<<dim3(512,8), 256, 0, stream>>>(fa);
  tab_kernel<<<8, 256, 0, stream>>>(TAB);

  // conv block: out = x + pw(silu(dwconv(ln1(x))))
  ln_kernel<<<BS_, 128, 0, stream>>>(x, ln1g, ln1b, XN);
  dwconv_kernel<<<2048, 256, 0, stream>>>(XN, dww, dwb, DWS);
  gemm_gl<false,true,true,false><<<dim3(8,64), 256, 0, stream>>>(
      DWS, WPW, pwb, x, out, nullptr, BS_, 512, 512);

  // attention block
  ln_kernel<<<BS_, 128, 0, stream>>>(out, ln2g, ln2b, XN);
  gemm_qkv<<<dim3(24,64), 256, 0, stream>>>(
      XN, WQ, qb, kb, vb, Q, Kb_, V, BS_, 512);
  gemm_pos<<<8, 256, 0, stream>>>(RELB, WK, kb, POSK, 1.f,    512, 512);
  gemm_pos<<<8, 256, 0, stream>>>(RELB, WQ, qb, POSQ, SCALE_, 512, 512);
  posbias_kernel<<<dim3(128,8), 256, 0, stream>>>(Q, Kb_, POSK, POSQ, C2P, P2C);
  vtrans_kernel<<<dim3(16,8,8), 256, 0, stream>>>(V, VT);
  flash_kernel<<<dim3(16,8,8), 256, 0, stream>>>(Q, Kb_, VT, C2P, P2C, TAB, CTX);
  gemm_gl<false,true,true,false><<<dim3(8,64), 256, 0, stream>>>(
      CTX, WO, ob, out, out, nullptr, BS_, 512, 512);

  // FFN block: out += w2 @ silu(w1 @ ln3(out))
  ln_kernel<<<BS_, 128, 0, stream>>>(out, ln3g, ln3b, XN);
  gemm_gl<true,false,false,true><<<dim3(16,64), 256, 0, stream>>>(
      XN, W1B, b1, nullptr, nullptr, FFH, BS_, 1024, 512);
  gemm_gl<false,true,true,false><<<dim3(8,64), 256, 0, stream>>>(
      FFH, W2B, b2, out, out, nullptr, BS_, 512, 1024);
}

// Round 6
// 325.719 us; speedup vs baseline: 1.5797x; 1.0761x over previous
//
#include <hip/hip_runtime.h>
#include <hip/hip_bf16.h>
#include <math.h>

// MEGConformerLayer: conv block + DeBERTa-v2 attention + FFN, all bf16 MFMA.
// B=8 S=1024 D=512 H=8 DH=64 K=3 FF=1024 BUCKETS=32 SPAN=32
// R6: XCD-locality swizzles. GEMM grids are m-major (gridDim.x = Mtiles = 64,
// 64%8==0 -> lin%8 = mtile%8: all n-tiles of an m-slab share an XCD; A-slab
// fetched from HBM once, then L2). Flash grid is (bh, it) so the 16 it-blocks
// sharing K/VT/P2C land on one XCD. No tiling changes vs R5.

#define B_  8
#define S_  1024
#define D_  512
#define H_  8
#define DH_ 64
#define FF_ 1024
#define BS_ (B_*S_)   // 8192
#define SCALE_ 0.07216878364f   // 1/sqrt(DH*3)

typedef __attribute__((ext_vector_type(8))) short  short8;
typedef __attribute__((ext_vector_type(4))) short  short4v;
typedef __attribute__((ext_vector_type(4))) float  f32x4;
typedef __attribute__((ext_vector_type(4))) int    int4v;

static __device__ __forceinline__ float b2f(short u){
  union { int i; float f; } cv; cv.i = ((int)(unsigned short)u) << 16; return cv.f;
}
static __device__ __forceinline__ short f2b(float f){
  union { float f; unsigned u; } cv; cv.f = f;
  unsigned r = cv.u + 0x7FFFu + ((cv.u >> 16) & 1u);  // RNE
  return (short)(r >> 16);
}
static __device__ __forceinline__ float silu_f(float x){
  return x / (1.f + __expf(-x));
}
static __device__ __forceinline__ f32x4 mfma16(short8 a, short8 b, f32x4 c){
  return __builtin_amdgcn_mfma_f32_16x16x32_bf16(a, b, c, 0, 0, 0);
}
// async global->LDS, 16B/lane; dest = wave-uniform base + lane*16
static __device__ __forceinline__ void gl16(const void* g, void* l){
  __builtin_amdgcn_global_load_lds((const __attribute__((address_space(1))) void*)g,
                                   (__attribute__((address_space(3))) void*)l, 16, 0, 0);
}

// ---------------- fused fp32 -> bf16 weight convert (8 segments, 1 launch) ----------------
struct F2B8 { const float* s[8]; short* d[8]; int n[8]; };
__global__ __launch_bounds__(256) void f2b8_kernel(F2B8 a){
  int seg = blockIdx.y;
  int i = (blockIdx.x*256 + threadIdx.x)*4;
  if (i >= a.n[seg]) return;
  float4 v = *(const float4*)(a.s[seg] + i);
  short4v o; o.x = f2b(v.x); o.y = f2b(v.y); o.z = f2b(v.z); o.w = f2b(v.w);
  *(short4v*)(a.d[seg] + i) = o;
}

// ---------------- DeBERTa log-bucket index table: delta=i-j in [-1023,1024] ----------------
__global__ __launch_bounds__(256) void tab_kernel(signed char* __restrict__ tab){
  int t = blockIdx.x*256 + threadIdx.x;
  if (t >= 2048) return;
  int d = t - 1023;
  int ad = d < 0 ? -d : d;
  int bkt;
  if (ad <= 16) bkt = d;
  else {
    const float inv_log = 15.f / logf(7.9375f);   // (mid-1)/log((MAX_REL-1)/mid)
    float lp = ceilf(logf((float)ad * (1.f/16.f)) * inv_log) + 16.f;
    int ilp = (int)lp;
    bkt = (d > 0) ? ilp : -ilp;
  }
  int idx = bkt + 32;
  idx = idx < 0 ? 0 : (idx > 63 ? 63 : idx);
  tab[t] = (signed char)idx;
}

// ---------------- LayerNorm (rows of 512), fp32 in -> bf16 out ----------------
__global__ __launch_bounds__(128) void ln_kernel(const float* __restrict__ x,
                                                 const float* __restrict__ g,
                                                 const float* __restrict__ bb,
                                                 short* __restrict__ out){
  int row = blockIdx.x;
  int tid = threadIdx.x;               // 128 threads * float4 = 512
  float4 v = ((const float4*)(x + (size_t)row*D_))[tid];
  float s  = v.x + v.y + v.z + v.w;
  float ss = v.x*v.x + v.y*v.y + v.z*v.z + v.w*v.w;
  #pragma unroll
  for (int off = 32; off; off >>= 1){ s += __shfl_down(s, off); ss += __shfl_down(ss, off); }
  __shared__ float red[4];
  if ((tid & 63) == 0){ red[tid>>6] = s; red[2 + (tid>>6)] = ss; }
  __syncthreads();
  float S  = red[0] + red[1];
  float SS = red[2] + red[3];
  float m   = S * (1.f/D_);
  float var = SS * (1.f/D_) - m*m;
  float rs  = rsqrtf(var + 1e-5f);
  float4 gv = ((const float4*)g)[tid];
  float4 bv = ((const float4*)bb)[tid];
  short4v o;
  o.x = f2b((v.x - m)*rs*gv.x + bv.x);
  o.y = f2b((v.y - m)*rs*gv.y + bv.y);
  o.z = f2b((v.z - m)*rs*gv.z + bv.z);
  o.w = f2b((v.w - m)*rs*gv.w + bv.w);
  *(short4v*)(out + (size_t)row*D_ + tid*4) = o;
}

// ---------------- depthwise conv (K=3, pad 1, per-seq) + SiLU, bf16->bf16 ----------------
__global__ __launch_bounds__(256) void dwconv_kernel(const short* __restrict__ xn,
                                                     const float* __restrict__ w,   // [D,1,3]
                                                     const float* __restrict__ bias,
                                                     short* __restrict__ out){
  int idx = blockIdx.x*256 + threadIdx.x;   // BS_*64 threads, 8 channels each
  int bs  = idx >> 6;
  int d8  = (idx & 63) << 3;
  int s   = bs & (S_-1);
  const short* base = xn + (size_t)bs*D_ + d8;
  short8 z = {};
  short8 xm = (s > 0)     ? *(const short8*)(base - D_) : z;
  short8 xc =               *(const short8*)(base);
  short8 xp = (s < S_-1)  ? *(const short8*)(base + D_) : z;
  short8 o;
  #pragma unroll
  for (int i = 0; i < 8; i++){
    int d = d8 + i;
    float acc = bias[d] + b2f(xm[i])*w[d*3+0] + b2f(xc[i])*w[d*3+1] + b2f(xp[i])*w[d*3+2];
    o[i] = f2b(silu_f(acc));
  }
  *(short8*)(out + (size_t)bs*D_ + d8) = o;
}

// ====== GEMM core with global_load_lds staging + XOR-swizzled unpadded LDS ======
// 128Mx64N tile, BK=64, 4 waves (2x2), each 64Mx32N. chunk c (16B) of row r
// stored at physical chunk c^(r&7) -> reads are 2-way-conflict-free.
// Grid is (Mtiles, Ntiles): m from blockIdx.x -> lin%8 = mtile%8 (Mtiles%8==0),
// so all n-tiles of an m-slab share an XCD (A re-reads hit that XCD's L2).
#define GEMM_GL_CORE(AP, WP, KK)                                               \
  __shared__ short a_lds[128*64];                                              \
  __shared__ short b_lds[64*64];                                               \
  int tid = threadIdx.x;                                                       \
  int w = tid >> 6, lane = tid & 63, quad = lane >> 4, l16 = lane & 15;        \
  int wm = (w >> 1) * 64, wn = (w & 1) * 32;                                   \
  int m0 = blockIdx.x * 128, n0 = blockIdx.y * 64;                             \
  const short* aptr[4]; const short* bptr[2];                                  \
  _Pragma("unroll")                                                            \
  for (int i = 0; i < 4; i++){                                                 \
    int slot = i*256 + tid;                                                    \
    int r = slot >> 3, c = (slot & 7) ^ (r & 7);                               \
    aptr[i] = AP + (size_t)(m0 + r)*KK + c*8;                                  \
  }                                                                            \
  _Pragma("unroll")                                                            \
  for (int i = 0; i < 2; i++){                                                 \
    int slot = i*256 + tid;                                                    \
    int r = slot >> 3, c = (slot & 7) ^ (r & 7);                               \
    bptr[i] = WP + (size_t)(n0 + r)*KK + c*8;                                  \
  }                                                                            \
  f32x4 acc[4][2] = {};                                                        \
  int sw = l16 & 7;                                                            \
  for (int kk = 0; kk < KK; kk += 64){                                         \
    _Pragma("unroll")                                                          \
    for (int i = 0; i < 4; i++) gl16(aptr[i] + kk, &a_lds[(i*256 + w*64)*8]);  \
    _Pragma("unroll")                                                          \
    for (int i = 0; i < 2; i++) gl16(bptr[i] + kk, &b_lds[(i*256 + w*64)*8]);  \
    __syncthreads();                                                           \
    _Pragma("unroll")                                                          \
    for (int ks = 0; ks < 2; ks++){                                            \
      short8 b0 = *(const short8*)&b_lds[(wn      + l16)*64 + ((ks*4+quad)^sw)*8]; \
      short8 b1 = *(const short8*)&b_lds[(wn + 16 + l16)*64 + ((ks*4+quad)^sw)*8]; \
      _Pragma("unroll")                                                        \
      for (int mt = 0; mt < 4; mt++){                                          \
        short8 a = *(const short8*)&a_lds[(wm + mt*16 + l16)*64 + ((ks*4+quad)^sw)*8]; \
        acc[mt][0] = mfma16(a, b0, acc[mt][0]);                                \
        acc[mt][1] = mfma16(a, b1, acc[mt][1]);                                \
      }                                                                        \
    }                                                                          \
    __syncthreads();                                                           \
  }

template<bool SILU, bool RES, bool OF32, bool OBF>
__global__ __launch_bounds__(256) void gemm_gl(const short* __restrict__ A,
                                               const short* __restrict__ W,
                                               const float* __restrict__ bias,
                                               const float* res,
                                               float* of32,
                                               short* __restrict__ obf,
                                               int M, int N, int K){
  GEMM_GL_CORE(A, W, K)
  #pragma unroll
  for (int mt = 0; mt < 4; mt++)
    #pragma unroll
    for (int nt = 0; nt < 2; nt++)
      #pragma unroll
      for (int r = 0; r < 4; r++){
        int row = m0 + wm + mt*16 + quad*4 + r;
        int col = n0 + wn + nt*16 + l16;
        float val = acc[mt][nt][r] + bias[col];
        if (SILU) val = silu_f(val);
        if (RES)  val += res[(size_t)row*N + col];
        if (OF32) of32[(size_t)row*N + col] = val;
        if (OBF)  obf[(size_t)row*N + col] = f2b(val);
      }
}

// fused QKV projection: W = [WQ;WK;WV] (1536x512 contiguous), outputs split,
// Q pre-scaled by SCALE_ (folds attention scale into QK^T and c2p).
__global__ __launch_bounds__(256) void gemm_qkv(const short* __restrict__ A,
                                                const short* __restrict__ W,
                                                const float* __restrict__ qb,
                                                const float* __restrict__ kb,
                                                const float* __restrict__ vb,
                                                short* __restrict__ Qo,
                                                short* __restrict__ Ko,
                                                short* __restrict__ Vo,
                                                int M, int K){
  GEMM_GL_CORE(A, W, K)
  int colb = n0 + wn;
  int sel = colb >> 9;                       // uniform per (block, wn, nt) tile
  const float* bp = sel == 0 ? qb : (sel == 1 ? kb : vb);
  short* dp = sel == 0 ? Qo : (sel == 1 ? Ko : Vo);
  float mult = sel == 0 ? SCALE_ : 1.f;
  #pragma unroll
  for (int mt = 0; mt < 4; mt++)
    #pragma unroll
    for (int nt = 0; nt < 2; nt++)
      #pragma unroll
      for (int r = 0; r < 4; r++){
        int row = m0 + wm + mt*16 + quad*4 + r;
        int col = (colb + nt*16 + l16) & 511;
        float val = (acc[mt][nt][r] + bp[col]) * mult;
        dp[(size_t)row*D_ + col] = f2b(val);
      }
}

// ---------------- GEMM 64x64 (two tiny M=64 pos-projection gemms) ----------------
__global__ __launch_bounds__(256) void gemm_pos(const short* __restrict__ A,
                                                const short* __restrict__ W,
                                                const float* __restrict__ bias,
                                                short* __restrict__ obf,
                                                float mult, int N, int K){
  __shared__ short a_lds[64][72];
  __shared__ short b_lds[64][72];
  int tid = threadIdx.x;
  int w = tid >> 6, lane = tid & 63, quad = lane >> 4, l16 = lane & 15;
  int wm = (w >> 1) * 32, wn = (w & 1) * 32;
  int m0 = 0, n0 = blockIdx.x * 64;
  int r0 = tid >> 3, c0 = (tid & 7) * 8;
  int r1 = r0 + 32;
  f32x4 acc[2][2] = {};
  for (int kk = 0; kk < K; kk += 64){
    *(int4v*)&a_lds[r0][c0] = *(const int4v*)(A + (size_t)(m0+r0)*K + kk + c0);
    *(int4v*)&a_lds[r1][c0] = *(const int4v*)(A + (size_t)(m0+r1)*K + kk + c0);
    *(int4v*)&b_lds[r0][c0] = *(const int4v*)(W + (size_t)(n0+r0)*K + kk + c0);
    *(int4v*)&b_lds[r1][c0] = *(const int4v*)(W + (size_t)(n0+r1)*K + kk + c0);
    __syncthreads();
    #pragma unroll
    for (int ks = 0; ks < 2; ks++){
      short8 a0 = *(const short8*)&a_lds[wm      + l16][ks*32 + quad*8];
      short8 a1 = *(const short8*)&a_lds[wm + 16 + l16][ks*32 + quad*8];
      short8 b0 = *(const short8*)&b_lds[wn      + l16][ks*32 + quad*8];
      short8 b1 = *(const short8*)&b_lds[wn + 16 + l16][ks*32 + quad*8];
      acc[0][0] = mfma16(a0, b0, acc[0][0]);
      acc[0][1] = mfma16(a0, b1, acc[0][1]);
      acc[1][0] = mfma16(a1, b0, acc[1][0]);
      acc[1][1] = mfma16(a1, b1, acc[1][1]);
    }
    __syncthreads();
  }
  #pragma unroll
  for (int mt = 0; mt < 2; mt++)
    #pragma unroll
    for (int nt = 0; nt < 2; nt++)
      #pragma unroll
      for (int r = 0; r < 4; r++){
        int row = m0 + wm + mt*16 + quad*4 + r;
        int col = n0 + wn + nt*16 + l16;
        obf[(size_t)row*N + col] = f2b((acc[mt][nt][r] + bias[col]) * mult);
      }
}

// ---------------- c2p/p2c position-bias batched GEMM ----------------
// q pre-scaled -> c2p scaled; posq pre-scaled -> p2c scaled.
__global__ __launch_bounds__(256) void posbias_kernel(const short* __restrict__ q,
                                                      const short* __restrict__ k,
                                                      const short* __restrict__ posk,
                                                      const short* __restrict__ posq,
                                                      short* __restrict__ c2p,
                                                      short* __restrict__ p2c){
  int bsT = blockIdx.x;          // 128 tiles of 64 rows
  int h   = blockIdx.y;
  int tid = threadIdx.x, w = tid >> 6, lane = tid & 63, quad = lane >> 4, l16 = lane & 15;
  int row_a = bsT*64 + w*16 + l16;
  f32x4 accc[4] = {}, accp[4] = {};
  #pragma unroll
  for (int ks = 0; ks < 2; ks++){
    short8 aq = *(const short8*)(q + (size_t)row_a*D_ + h*DH_ + ks*32 + quad*8);
    short8 ak = *(const short8*)(k + (size_t)row_a*D_ + h*DH_ + ks*32 + quad*8);
    #pragma unroll
    for (int nt = 0; nt < 4; nt++){
      short8 bk = *(const short8*)(posk + (size_t)(nt*16+l16)*D_ + h*DH_ + ks*32 + quad*8);
      short8 bq = *(const short8*)(posq + (size_t)(nt*16+l16)*D_ + h*DH_ + ks*32 + quad*8);
      accc[nt] = mfma16(aq, bk, accc[nt]);
      accp[nt] = mfma16(ak, bq, accp[nt]);
    }
  }
  #pragma unroll
  for (int nt = 0; nt < 4; nt++)
    #pragma unroll
    for (int r = 0; r < 4; r++){
      int row = bsT*64 + w*16 + quad*4 + r;
      int col = h*DH_ + nt*16 + l16;
      c2p[(size_t)row*D_ + col] = f2b(accc[nt][r]);
      p2c[(size_t)row*D_ + col] = f2b(accp[nt][r]);
    }
}

// ---------------- V -> VT[B,H,DH,S] pre-transpose (65-pad: 2-way conflicts = free) ------
__global__ __launch_bounds__(256) void vtrans_kernel(const short* __restrict__ v,
                                                     short* __restrict__ vt){
  __shared__ short t_lds[64][65];
  int st = blockIdx.x, h = blockIdx.y, b = blockIdx.z;
  int s0 = st*64;
  int tid = threadIdx.x;
  #pragma unroll
  for (int i = 0; i < 2; i++){
    int c = i*256 + tid;
    int s = c >> 3, d8 = (c & 7) * 8;
    short8 vv = *(const short8*)(v + (size_t)(b*S_ + s0 + s)*D_ + h*DH_ + d8);
    #pragma unroll
    for (int jj = 0; jj < 8; jj++) t_lds[d8+jj][s] = vv[jj];
  }
  __syncthreads();
  #pragma unroll
  for (int i = 0; i < 2; i++){
    int c = i*256 + tid;
    int d = c >> 3, s8 = (c & 7) * 8;
    short8 o;
    #pragma unroll
    for (int jj = 0; jj < 8; jj++) o[jj] = t_lds[d][s8+jj];
    *(short8*)(vt + ((size_t)(b*H_ + h)*DH_ + d)*S_ + s0 + s8) = o;
  }
}

// ---------------- flash attention v6: v5 + (bh, it) grid for XCD/L2 locality ------------
// grid = (bh=64, it=16): lin%8 = bh%8 -> all 16 it-blocks of one (b,h) share
// an XCD; their common K/VT/P2C slices (~384 KB) stay L2-resident.
#define PPS 68
__global__ __launch_bounds__(256, 4) void flash_kernel(const short* __restrict__ q,
                                                       const short* __restrict__ k,
                                                       const short* __restrict__ VT,
                                                       const short* __restrict__ c2p,
                                                       const short* __restrict__ p2c,
                                                       const signed char* __restrict__ TAB,
                                                       short* __restrict__ ctx){
  __shared__ short k_lds[64][72];
  __shared__ short v_lds[64][72];     // VT tile: [d][s_local]
  __shared__ short c2p_lds[64][72];
  __shared__ short pp_lds[64][PPS];   // p2c tile, then P matrix
  __shared__ signed char tab[2048];

  int bh = blockIdx.x, it = blockIdx.y;
  int b = bh >> 3, h = bh & 7;
  int i0 = it * 64;
  int tid = threadIdx.x, w = tid >> 6, lane = tid & 63, quad = lane >> 4, l16 = lane & 15;

  ((unsigned long long*)tab)[tid] = ((const unsigned long long*)TAB)[tid];  // 2048 B
  #pragma unroll
  for (int i = 0; i < 2; i++){
    int c = i*256 + tid;
    int r = c >> 3, cc = (c & 7) * 8;
    *(int4v*)&c2p_lds[r][cc] = *(const int4v*)(c2p + (size_t)(b*S_ + i0 + r)*D_ + h*DH_ + cc);
  }
  short8 qf0, qf1;
  {
    size_t row = (size_t)(b*S_ + i0 + w*16 + l16);
    qf0 = *(const short8*)(q + row*D_ + h*DH_ +      quad*8);
    qf1 = *(const short8*)(q + row*D_ + h*DH_ + 32 + quad*8);
  }
  __syncthreads();

  float cpos[4], cneg[4];
  #pragma unroll
  for (int r = 0; r < 4; r++){
    int iloc = w*16 + quad*4 + r;
    cpos[r] = b2f(c2p_lds[iloc][63]);   // saturated idx, i-j >= 129
    cneg[r] = b2f(c2p_lds[iloc][0]);    // saturated idx, i-j <= -129
  }
  f32x4 o_acc[4] = {};
  float lrow[4] = {};                    // per-lane partial sums
  const short* Kbase  = k   + (size_t)(b*S_)*D_ + h*DH_;
  const short* VTbase = VT  + (size_t)(b*H_ + h)*DH_*S_;
  const short* Pbase  = p2c + (size_t)(b*S_)*D_ + h*DH_;

  int st_r = tid >> 3, st_c = (tid & 7) * 8;   // staging coords (rows 0..31)

  for (int jt = 0; jt < 16; jt++){
    int j0 = jt * 64;
    bool near = (jt >= it-2 && jt <= it+2);
    // ---- stage K, VT, p2c tiles (coalesced 128B row-segments) ----
    #pragma unroll
    for (int i = 0; i < 2; i++){
      int r = st_r + i*32;
      *(int4v*)&k_lds[r][st_c]  = *(const int4v*)(Kbase + (size_t)(j0 + r)*D_ + st_c);
      *(int4v*)&v_lds[r][st_c]  = *(const int4v*)(VTbase + (size_t)r*S_ + j0 + st_c);
      *(int4v*)&pp_lds[r][st_c] = *(const int4v*)(Pbase + (size_t)(j0 + r)*D_ + st_c);
    }
    __syncthreads();

    // ---- S = Q K^T (per wave: 16 rows x 64 cols), already scaled ----
    f32x4 sfr[4];
    #pragma unroll
    for (int nt = 0; nt < 4; nt++){
      f32x4 a = {};
      a = mfma16(qf0, *(const short8*)&k_lds[nt*16+l16][     quad*8], a);
      a = mfma16(qf1, *(const short8*)&k_lds[nt*16+l16][32 + quad*8], a);
      sfr[nt] = a;
    }
    // ---- P = exp(S + c2p + p2c); accumulate per-lane l partials ----
    float pval[4][4];
    if (near){
      #pragma unroll
      for (int nt = 0; nt < 4; nt++){
        int jloc = nt*16 + l16;
        #pragma unroll
        for (int r = 0; r < 4; r++){
          int iloc = w*16 + quad*4 + r;
          int idx  = tab[(i0 + iloc) - (j0 + jloc) + 1023];
          float p = __expf(sfr[nt][r] + b2f(c2p_lds[iloc][idx]) + b2f(pp_lds[jloc][idx]));
          pval[nt][r] = p;
          lrow[r] += p;
        }
      }
    } else {
      int cidx = (jt < it) ? 63 : 0;
      const float* cP = (jt < it) ? cpos : cneg;
      #pragma unroll
      for (int nt = 0; nt < 4; nt++){
        float pv = b2f(pp_lds[nt*16 + l16][cidx]);
        #pragma unroll
        for (int r = 0; r < 4; r++){
          float p = __expf(sfr[nt][r] + cP[r] + pv);
          pval[nt][r] = p;
          lrow[r] += p;
        }
      }
    }
    __syncthreads();   // all waves done reading pp_lds (p2c) before P overwrite

    // ---- P: C-layout -> A-layout via wave-private pp_lds band ----
    #pragma unroll
    for (int nt = 0; nt < 4; nt++)
      #pragma unroll
      for (int r = 0; r < 4; r++)
        pp_lds[w*16 + quad*4 + r][nt*16 + l16] = f2b(pval[nt][r]);
    short8 pf0 = *(const short8*)&pp_lds[w*16 + l16][     quad*8];
    short8 pf1 = *(const short8*)&pp_lds[w*16 + l16][32 + quad*8];
    // ---- O += P V ----
    #pragma unroll
    for (int nt = 0; nt < 4; nt++){
      o_acc[nt] = mfma16(pf0, *(const short8*)&v_lds[nt*16+l16][     quad*8], o_acc[nt]);
      o_acc[nt] = mfma16(pf1, *(const short8*)&v_lds[nt*16+l16][32 + quad*8], o_acc[nt]);
    }
    __syncthreads();   // protect k/v/pp before next tile's staging
  }
  // final row-sum reduction over the 16 lanes of each quad group
  #pragma unroll
  for (int r = 0; r < 4; r++){
    #pragma unroll
    for (int off = 8; off; off >>= 1) lrow[r] += __shfl_xor(lrow[r], off);
  }
  #pragma unroll
  for (int nt = 0; nt < 4; nt++)
    #pragma unroll
    for (int r = 0; r < 4; r++){
      size_t row = (size_t)(b*S_ + i0 + w*16 + quad*4 + r);
      ctx[row*D_ + h*DH_ + nt*16 + l16] = f2b(o_acc[nt][r] / lrow[r]);
    }
}

// ---------------- workspace layout (bytes) — high-water 55,248,896 (~52.7 MB) ----------------
// Aliases: DWS = C2P span (dead before posbias); VT = XN span (XN dead after
// qkv gemm); CTX = V span (V dead after vtrans); FFH = Q..K span (dead after
// flash); fp32 residual chain lives in d_out (same-thread RMW in epilogues).
static const size_t OFF_XN   = 0;           // bf16 8192x512  (alias: VT)
static const size_t OFF_Q    = 8388608;     // bf16 8192x512  (alias: FFH lo)
static const size_t OFF_K    = 16777216;    // bf16 8192x512  (alias: FFH hi)
static const size_t OFF_V    = 25165824;    // bf16 8192x512  (alias: CTX)
static const size_t OFF_C2P  = 33554432;    // bf16 8192x512  (alias: DWS)
static const size_t OFF_P2C  = 41943040;    // bf16 8192x512
static const size_t OFF_WPW  = 50331648;    // bf16 512x512
static const size_t OFF_WQ   = 50855936;    // WQ/WK/WV contiguous = [1536,512]
static const size_t OFF_WK   = 51380224;
static const size_t OFF_WV   = 51904512;
static const size_t OFF_WO   = 52428800;
static const size_t OFF_W1   = 52953088;    // bf16 1024x512
static const size_t OFF_W2   = 54001664;    // bf16 512x1024
static const size_t OFF_REL  = 55050240;    // bf16 64x512
static const size_t OFF_POSK = 55115776;    // bf16 64x512
static const size_t OFF_POSQ = 55181312;    // bf16 64x512
static const size_t OFF_TAB  = 55246848;    // int8 2048

extern "C" void kernel_launch(void* const* d_in, const int* in_sizes, int n_in,
                              void* d_out, int out_size, void* d_ws, size_t ws_size,
                              hipStream_t stream){
  const float* x    = (const float*)d_in[0];
  const float* ln1g = (const float*)d_in[1];
  const float* ln1b = (const float*)d_in[2];
  const float* dww  = (const float*)d_in[3];
  const float* dwb  = (const float*)d_in[4];
  const float* pww  = (const float*)d_in[5];
  const float* pwb  = (const float*)d_in[6];
  const float* ln2g = (const float*)d_in[7];
  const float* ln2b = (const float*)d_in[8];
  const float* qw   = (const float*)d_in[9];
  const float* qb   = (const float*)d_in[10];
  const float* kw   = (const float*)d_in[11];
  const float* kb   = (const float*)d_in[12];
  const float* vw   = (const float*)d_in[13];
  const float* vb   = (const float*)d_in[14];
  const float* ow   = (const float*)d_in[15];
  const float* ob   = (const float*)d_in[16];
  const float* rel  = (const float*)d_in[17];
  const float* ln3g = (const float*)d_in[18];
  const float* ln3b = (const float*)d_in[19];
  const float* w1   = (const float*)d_in[20];
  const float* b1   = (const float*)d_in[21];
  const float* w2   = (const float*)d_in[22];
  const float* b2   = (const float*)d_in[23];
  float* out = (float*)d_out;
  char* ws = (char*)d_ws;

  short* XN   = (short*)(ws + OFF_XN);
  short* Q    = (short*)(ws + OFF_Q);
  short* Kb_  = (short*)(ws + OFF_K);
  short* V    = (short*)(ws + OFF_V);
  short* C2P  = (short*)(ws + OFF_C2P);
  short* P2C  = (short*)(ws + OFF_P2C);
  short* WPW  = (short*)(ws + OFF_WPW);
  short* WQ   = (short*)(ws + OFF_WQ);
  short* WK   = (short*)(ws + OFF_WK);
  short* WV   = (short*)(ws + OFF_WV);
  short* WO   = (short*)(ws + OFF_WO);
  short* W1B  = (short*)(ws + OFF_W1);
  short* W2B  = (short*)(ws + OFF_W2);
  short* RELB = (short*)(ws + OFF_REL);
  short* POSK = (short*)(ws + OFF_POSK);
  short* POSQ = (short*)(ws + OFF_POSQ);
  signed char* TAB = (signed char*)(ws + OFF_TAB);
  short* DWS  = C2P;     // alias
  short* VT   = XN;      // alias
  short* CTX  = V;       // alias
  short* FFH  = Q;       // alias (16 MB over Q+K)

  // fused weight conversions + bucket table
  F2B8 fa;
  fa.s[0]=pww; fa.d[0]=WPW; fa.n[0]=262144;
  fa.s[1]=qw;  fa.d[1]=WQ;  fa.n[1]=262144;
  fa.s[2]=kw;  fa.d[2]=WK;  fa.n[2]=262144;
  fa.s[3]=vw;  fa.d[3]=WV;  fa.n[3]=262144;
  fa.s[4]=ow;  fa.d[4]=WO;  fa.n[4]=262144;
  fa.s[5]=w1;  fa.d[5]=W1B; fa.n[5]=524288;
  fa.s[6]=w2;  fa.d[6]=W2B; fa.n[6]=524288;
  fa.s[7]=rel; fa.d[7]=RELB;fa.n[7]=32768;
  f2b8_kernel<<<dim3(512,8), 256, 0, stream>>>(fa);
  tab_kernel<<<8, 256, 0, stream>>>(TAB);

  // conv block: out = x + pw(silu(dwconv(ln1(x))))
  ln_kernel<<<BS_, 128, 0, stream>>>(x, ln1g, ln1b, XN);
  dwconv_kernel<<<2048, 256, 0, stream>>>(XN, dww, dwb, DWS);
  gemm_gl<false,true,true,false><<<dim3(64,8), 256, 0, stream>>>(
      DWS, WPW, pwb, x, out, nullptr, BS_, 512, 512);

  // attention block
  ln_kernel<<<BS_, 128, 0, stream>>>(out, ln2g, ln2b, XN);
  gemm_qkv<<<dim3(64,24), 256, 0, stream>>>(
      XN, WQ, qb, kb, vb, Q, Kb_, V, BS_, 512);
  gemm_pos<<<8, 256, 0, stream>>>(RELB, WK, kb, POSK, 1.f,    512, 512);
  gemm_pos<<<8, 256, 0, stream>>>(RELB, WQ, qb, POSQ, SCALE_, 512, 512);
  posbias_kernel<<<dim3(128,8), 256, 0, stream>>>(Q, Kb_, POSK, POSQ, C2P, P2C);
  vtrans_kernel<<<dim3(16,8,8), 256, 0, stream>>>(V, VT);
  flash_kernel<<<dim3(64,16), 256, 0, stream>>>(Q, Kb_, VT, C2P, P2C, TAB, CTX);
  gemm_gl<false,true,true,false><<<dim3(64,8), 256, 0, stream>>>(
      CTX, WO, ob, out, out, nullptr, BS_, 512, 512);

  // FFN block: out += w2 @ silu(w1 @ ln3(out))
  ln_kernel<<<BS_, 128, 0, stream>>>(out, ln3g, ln3b, XN);
  gemm_gl<true,false,false,true><<<dim3(64,16), 256, 0, stream>>>(
      XN, W1B, b1, nullptr, nullptr, FFH, BS_, 1024, 512);
  gemm_gl<false,true,true,false><<<dim3(64,8), 256, 0, stream>>>(
      FFH, W2B, b2, out, out, nullptr, BS_, 512, 1024);
}

// Round 7
// 323.246 us; speedup vs baseline: 1.5918x; 1.0077x over previous
//
#include <hip/hip_runtime.h>
#include <hip/hip_bf16.h>
#include <math.h>

// MEGConformerLayer: conv block + DeBERTa-v2 attention + FFN, all bf16 MFMA.
// B=8 S=1024 D=512 H=8 DH=64 K=3 FF=1024 BUCKETS=32 SPAN=32
// R7: GEMM K-loop -> single-barrier double-buffered DMA (prefetch issued
// AFTER the barrier so the vmcnt(0) drain lands one compute-phase later).
// Flash: DMA-staged K/V (XOR swizzle, unpadded), p2c staged only for near
// tiles, far tiles read precomputed PFAR columns; 2 barriers on far tiles.

#define B_  8
#define S_  1024
#define D_  512
#define H_  8
#define DH_ 64
#define FF_ 1024
#define BS_ (B_*S_)   // 8192
#define SCALE_ 0.07216878364f   // 1/sqrt(DH*3)

typedef __attribute__((ext_vector_type(8))) short  short8;
typedef __attribute__((ext_vector_type(4))) short  short4v;
typedef __attribute__((ext_vector_type(4))) float  f32x4;
typedef __attribute__((ext_vector_type(4))) int    int4v;

static __device__ __forceinline__ float b2f(short u){
  union { int i; float f; } cv; cv.i = ((int)(unsigned short)u) << 16; return cv.f;
}
static __device__ __forceinline__ short f2b(float f){
  union { float f; unsigned u; } cv; cv.f = f;
  unsigned r = cv.u + 0x7FFFu + ((cv.u >> 16) & 1u);  // RNE
  return (short)(r >> 16);
}
static __device__ __forceinline__ float silu_f(float x){
  return x / (1.f + __expf(-x));
}
static __device__ __forceinline__ f32x4 mfma16(short8 a, short8 b, f32x4 c){
  return __builtin_amdgcn_mfma_f32_16x16x32_bf16(a, b, c, 0, 0, 0);
}
// async global->LDS, 16B/lane; dest = wave-uniform base + lane*16
static __device__ __forceinline__ void gl16(const void* g, void* l){
  __builtin_amdgcn_global_load_lds((const __attribute__((address_space(1))) void*)g,
                                   (__attribute__((address_space(3))) void*)l, 16, 0, 0);
}

// ---------------- fused fp32 -> bf16 weight convert (8 segments, 1 launch) ----------------
struct F2B8 { const float* s[8]; short* d[8]; int n[8]; };
__global__ __launch_bounds__(256) void f2b8_kernel(F2B8 a){
  int seg = blockIdx.y;
  int i = (blockIdx.x*256 + threadIdx.x)*4;
  if (i >= a.n[seg]) return;
  float4 v = *(const float4*)(a.s[seg] + i);
  short4v o; o.x = f2b(v.x); o.y = f2b(v.y); o.z = f2b(v.z); o.w = f2b(v.w);
  *(short4v*)(a.d[seg] + i) = o;
}

// ---------------- DeBERTa log-bucket index table: delta=i-j in [-1023,1024] ----------------
__global__ __launch_bounds__(256) void tab_kernel(signed char* __restrict__ tab){
  int t = blockIdx.x*256 + threadIdx.x;
  if (t >= 2048) return;
  int d = t - 1023;
  int ad = d < 0 ? -d : d;
  int bkt;
  if (ad <= 16) bkt = d;
  else {
    const float inv_log = 15.f / logf(7.9375f);   // (mid-1)/log((MAX_REL-1)/mid)
    float lp = ceilf(logf((float)ad * (1.f/16.f)) * inv_log) + 16.f;
    int ilp = (int)lp;
    bkt = (d > 0) ? ilp : -ilp;
  }
  int idx = bkt + 32;
  idx = idx < 0 ? 0 : (idx > 63 ? 63 : idx);
  tab[t] = (signed char)idx;
}

// ---------------- LayerNorm (rows of 512), fp32 in -> bf16 out ----------------
__global__ __launch_bounds__(128) void ln_kernel(const float* __restrict__ x,
                                                 const float* __restrict__ g,
                                                 const float* __restrict__ bb,
                                                 short* __restrict__ out){
  int row = blockIdx.x;
  int tid = threadIdx.x;               // 128 threads * float4 = 512
  float4 v = ((const float4*)(x + (size_t)row*D_))[tid];
  float s  = v.x + v.y + v.z + v.w;
  float ss = v.x*v.x + v.y*v.y + v.z*v.z + v.w*v.w;
  #pragma unroll
  for (int off = 32; off; off >>= 1){ s += __shfl_down(s, off); ss += __shfl_down(ss, off); }
  __shared__ float red[4];
  if ((tid & 63) == 0){ red[tid>>6] = s; red[2 + (tid>>6)] = ss; }
  __syncthreads();
  float S  = red[0] + red[1];
  float SS = red[2] + red[3];
  float m   = S * (1.f/D_);
  float var = SS * (1.f/D_) - m*m;
  float rs  = rsqrtf(var + 1e-5f);
  float4 gv = ((const float4*)g)[tid];
  float4 bv = ((const float4*)bb)[tid];
  short4v o;
  o.x = f2b((v.x - m)*rs*gv.x + bv.x);
  o.y = f2b((v.y - m)*rs*gv.y + bv.y);
  o.z = f2b((v.z - m)*rs*gv.z + bv.z);
  o.w = f2b((v.w - m)*rs*gv.w + bv.w);
  *(short4v*)(out + (size_t)row*D_ + tid*4) = o;
}

// ---------------- depthwise conv (K=3, pad 1, per-seq) + SiLU, bf16->bf16 ----------------
__global__ __launch_bounds__(256) void dwconv_kernel(const short* __restrict__ xn,
                                                     const float* __restrict__ w,   // [D,1,3]
                                                     const float* __restrict__ bias,
                                                     short* __restrict__ out){
  int idx = blockIdx.x*256 + threadIdx.x;   // BS_*64 threads, 8 channels each
  int bs  = idx >> 6;
  int d8  = (idx & 63) << 3;
  int s   = bs & (S_-1);
  const short* base = xn + (size_t)bs*D_ + d8;
  short8 z = {};
  short8 xm = (s > 0)     ? *(const short8*)(base - D_) : z;
  short8 xc =               *(const short8*)(base);
  short8 xp = (s < S_-1)  ? *(const short8*)(base + D_) : z;
  short8 o;
  #pragma unroll
  for (int i = 0; i < 8; i++){
    int d = d8 + i;
    float acc = bias[d] + b2f(xm[i])*w[d*3+0] + b2f(xc[i])*w[d*3+1] + b2f(xp[i])*w[d*3+2];
    o[i] = f2b(silu_f(acc));
  }
  *(short8*)(out + (size_t)bs*D_ + d8) = o;
}

// ====== GEMM core: 128Mx64N, BK=64, double-buffered DMA, single barrier/step ======
// XOR swizzle: phys chunk c_p of row r holds logical chunk c_p^(r&7).
// DMA lane l of a row-group [base..base+7]: row base+(l>>3), src chunk (l&7)^(l>>3).
// Prefetch for step k+1 is issued AFTER the barrier of step k, so the
// compiler's vmcnt(0) drain at step k+1's barrier waits for loads that
// overlapped a full compute phase.
#define GEMM_GL_CORE(AP, WP, KK)                                               \
  __shared__ short a_lds[2][128*64];                                           \
  __shared__ short b_lds[2][64*64];                                            \
  int tid = threadIdx.x;                                                       \
  int w = tid >> 6, lane = tid & 63, quad = lane >> 4, l16 = lane & 15;        \
  int wm = (w >> 1) * 64, wn = (w & 1) * 32;                                   \
  int m0 = blockIdx.x * 128, n0 = blockIdx.y * 64;                             \
  int lr = lane >> 3, lc8 = ((lane & 7) ^ lr) * 8;                             \
  const short* asrc[4]; const short* bsrc[2];                                  \
  _Pragma("unroll")                                                            \
  for (int i = 0; i < 4; i++)                                                  \
    asrc[i] = AP + (size_t)(m0 + w*32 + i*8 + lr)*KK + lc8;                    \
  _Pragma("unroll")                                                            \
  for (int i = 0; i < 2; i++)                                                  \
    bsrc[i] = WP + (size_t)(n0 + w*16 + i*8 + lr)*KK + lc8;                    \
  f32x4 acc[4][2] = {};                                                        \
  int sx = l16 & 7;                                                            \
  _Pragma("unroll")                                                            \
  for (int i = 0; i < 4; i++) gl16(asrc[i], &a_lds[0][(w*32 + i*8)*64]);       \
  _Pragma("unroll")                                                            \
  for (int i = 0; i < 2; i++) gl16(bsrc[i], &b_lds[0][(w*16 + i*8)*64]);       \
  int cur = 0;                                                                 \
  for (int kk = 0; kk < KK; kk += 64){                                         \
    __syncthreads();                                                           \
    if (kk + 64 < KK){                                                         \
      _Pragma("unroll")                                                        \
      for (int i = 0; i < 4; i++)                                              \
        gl16(asrc[i] + kk + 64, &a_lds[cur^1][(w*32 + i*8)*64]);               \
      _Pragma("unroll")                                                        \
      for (int i = 0; i < 2; i++)                                              \
        gl16(bsrc[i] + kk + 64, &b_lds[cur^1][(w*16 + i*8)*64]);               \
    }                                                                          \
    _Pragma("unroll")                                                          \
    for (int ks = 0; ks < 2; ks++){                                            \
      short8 b0 = *(const short8*)&b_lds[cur][((wn      + l16)<<6) + (((ks*4+quad)^sx)<<3)]; \
      short8 b1 = *(const short8*)&b_lds[cur][((wn + 16 + l16)<<6) + (((ks*4+quad)^sx)<<3)]; \
      _Pragma("unroll")                                                        \
      for (int mt = 0; mt < 4; mt++){                                          \
        short8 a = *(const short8*)&a_lds[cur][((wm + mt*16 + l16)<<6) + (((ks*4+quad)^sx)<<3)]; \
        acc[mt][0] = mfma16(a, b0, acc[mt][0]);                                \
        acc[mt][1] = mfma16(a, b1, acc[mt][1]);                                \
      }                                                                        \
    }                                                                          \
    cur ^= 1;                                                                  \
  }

template<bool SILU, bool RES, bool OF32, bool OBF>
__global__ __launch_bounds__(256) void gemm_gl(const short* __restrict__ A,
                                               const short* __restrict__ W,
                                               const float* __restrict__ bias,
                                               const float* res,
                                               float* of32,
                                               short* __restrict__ obf,
                                               int M, int N, int K){
  GEMM_GL_CORE(A, W, K)
  #pragma unroll
  for (int mt = 0; mt < 4; mt++)
    #pragma unroll
    for (int nt = 0; nt < 2; nt++)
      #pragma unroll
      for (int r = 0; r < 4; r++){
        int row = m0 + wm + mt*16 + quad*4 + r;
        int col = n0 + wn + nt*16 + l16;
        float val = acc[mt][nt][r] + bias[col];
        if (SILU) val = silu_f(val);
        if (RES)  val += res[(size_t)row*N + col];
        if (OF32) of32[(size_t)row*N + col] = val;
        if (OBF)  obf[(size_t)row*N + col] = f2b(val);
      }
}

// fused QKV projection: W = [WQ;WK;WV] (1536x512 contiguous), outputs split,
// Q pre-scaled by SCALE_ (folds attention scale into QK^T and c2p).
__global__ __launch_bounds__(256) void gemm_qkv(const short* __restrict__ A,
                                                const short* __restrict__ W,
                                                const float* __restrict__ qb,
                                                const float* __restrict__ kb,
                                                const float* __restrict__ vb,
                                                short* __restrict__ Qo,
                                                short* __restrict__ Ko,
                                                short* __restrict__ Vo,
                                                int M, int K){
  GEMM_GL_CORE(A, W, K)
  int colb = n0 + wn;
  int sel = colb >> 9;                       // uniform per (block, wn) tile
  const float* bp = sel == 0 ? qb : (sel == 1 ? kb : vb);
  short* dp = sel == 0 ? Qo : (sel == 1 ? Ko : Vo);
  float mult = sel == 0 ? SCALE_ : 1.f;
  #pragma unroll
  for (int mt = 0; mt < 4; mt++)
    #pragma unroll
    for (int nt = 0; nt < 2; nt++)
      #pragma unroll
      for (int r = 0; r < 4; r++){
        int row = m0 + wm + mt*16 + quad*4 + r;
        int col = (colb + nt*16 + l16) & 511;
        float val = (acc[mt][nt][r] + bp[col]) * mult;
        dp[(size_t)row*D_ + col] = f2b(val);
      }
}

// ---------------- GEMM 64x64 (two tiny M=64 pos-projection gemms) ----------------
__global__ __launch_bounds__(256) void gemm_pos(const short* __restrict__ A,
                                                const short* __restrict__ W,
                                                const float* __restrict__ bias,
                                                short* __restrict__ obf,
                                                float mult, int N, int K){
  __shared__ short a_lds[64][72];
  __shared__ short b_lds[64][72];
  int tid = threadIdx.x;
  int w = tid >> 6, lane = tid & 63, quad = lane >> 4, l16 = lane & 15;
  int wm = (w >> 1) * 32, wn = (w & 1) * 32;
  int m0 = 0, n0 = blockIdx.x * 64;
  int r0 = tid >> 3, c0 = (tid & 7) * 8;
  int r1 = r0 + 32;
  f32x4 acc[2][2] = {};
  for (int kk = 0; kk < K; kk += 64){
    *(int4v*)&a_lds[r0][c0] = *(const int4v*)(A + (size_t)(m0+r0)*K + kk + c0);
    *(int4v*)&a_lds[r1][c0] = *(const int4v*)(A + (size_t)(m0+r1)*K + kk + c0);
    *(int4v*)&b_lds[r0][c0] = *(const int4v*)(W + (size_t)(n0+r0)*K + kk + c0);
    *(int4v*)&b_lds[r1][c0] = *(const int4v*)(W + (size_t)(n0+r1)*K + kk + c0);
    __syncthreads();
    #pragma unroll
    for (int ks = 0; ks < 2; ks++){
      short8 a0 = *(const short8*)&a_lds[wm      + l16][ks*32 + quad*8];
      short8 a1 = *(const short8*)&a_lds[wm + 16 + l16][ks*32 + quad*8];
      short8 b0 = *(const short8*)&b_lds[wn      + l16][ks*32 + quad*8];
      short8 b1 = *(const short8*)&b_lds[wn + 16 + l16][ks*32 + quad*8];
      acc[0][0] = mfma16(a0, b0, acc[0][0]);
      acc[0][1] = mfma16(a0, b1, acc[0][1]);
      acc[1][0] = mfma16(a1, b0, acc[1][0]);
      acc[1][1] = mfma16(a1, b1, acc[1][1]);
    }
    __syncthreads();
  }
  #pragma unroll
  for (int mt = 0; mt < 2; mt++)
    #pragma unroll
    for (int nt = 0; nt < 2; nt++)
      #pragma unroll
      for (int r = 0; r < 4; r++){
        int row = m0 + wm + mt*16 + quad*4 + r;
        int col = n0 + wn + nt*16 + l16;
        obf[(size_t)row*N + col] = f2b((acc[mt][nt][r] + bias[col]) * mult);
      }
}

// ---------------- c2p/p2c position-bias batched GEMM (+ PFAR columns) ----------------
// q pre-scaled -> c2p scaled; posq pre-scaled -> p2c scaled.
// PFAR[bh][0][s] = p2c[s][h*64+0], PFAR[bh][1][s] = p2c[s][h*64+63] (bf16).
__global__ __launch_bounds__(256) void posbias_kernel(const short* __restrict__ q,
                                                      const short* __restrict__ k,
                                                      const short* __restrict__ posk,
                                                      const short* __restrict__ posq,
                                                      short* __restrict__ c2p,
                                                      short* __restrict__ p2c,
                                                      short* __restrict__ pfar){
  int bsT = blockIdx.x;          // 128 tiles of 64 rows
  int h   = blockIdx.y;
  int tid = threadIdx.x, w = tid >> 6, lane = tid & 63, quad = lane >> 4, l16 = lane & 15;
  int row_a = bsT*64 + w*16 + l16;
  f32x4 accc[4] = {}, accp[4] = {};
  #pragma unroll
  for (int ks = 0; ks < 2; ks++){
    short8 aq = *(const short8*)(q + (size_t)row_a*D_ + h*DH_ + ks*32 + quad*8);
    short8 ak = *(const short8*)(k + (size_t)row_a*D_ + h*DH_ + ks*32 + quad*8);
    #pragma unroll
    for (int nt = 0; nt < 4; nt++){
      short8 bk = *(const short8*)(posk + (size_t)(nt*16+l16)*D_ + h*DH_ + ks*32 + quad*8);
      short8 bq = *(const short8*)(posq + (size_t)(nt*16+l16)*D_ + h*DH_ + ks*32 + quad*8);
      accc[nt] = mfma16(aq, bk, accc[nt]);
      accp[nt] = mfma16(ak, bq, accp[nt]);
    }
  }
  #pragma unroll
  for (int nt = 0; nt < 4; nt++)
    #pragma unroll
    for (int r = 0; r < 4; r++){
      int row = bsT*64 + w*16 + quad*4 + r;
      int col = h*DH_ + nt*16 + l16;
      short pv = f2b(accp[nt][r]);
      c2p[(size_t)row*D_ + col] = f2b(accc[nt][r]);
      p2c[(size_t)row*D_ + col] = pv;
      int cin = nt*16 + l16;          // column within head, 0..63
      if (cin == 0 || cin == 63){
        int b  = row >> 10, s = row & 1023;
        int bh = b*H_ + h;
        pfar[(size_t)bh*2048 + (cin ? 1024 : 0) + s] = pv;
      }
    }
}

// ---------------- V -> VT[B,H,DH,S] pre-transpose (65-pad: 2-way conflicts = free) ------
__global__ __launch_bounds__(256) void vtrans_kernel(const short* __restrict__ v,
                                                     short* __restrict__ vt){
  __shared__ short t_lds[64][65];
  int st = blockIdx.x, h = blockIdx.y, b = blockIdx.z;
  int s0 = st*64;
  int tid = threadIdx.x;
  #pragma unroll
  for (int i = 0; i < 2; i++){
    int c = i*256 + tid;
    int s = c >> 3, d8 = (c & 7) * 8;
    short8 vv = *(const short8*)(v + (size_t)(b*S_ + s0 + s)*D_ + h*DH_ + d8);
    #pragma unroll
    for (int jj = 0; jj < 8; jj++) t_lds[d8+jj][s] = vv[jj];
  }
  __syncthreads();
  #pragma unroll
  for (int i = 0; i < 2; i++){
    int c = i*256 + tid;
    int d = c >> 3, s8 = (c & 7) * 8;
    short8 o;
    #pragma unroll
    for (int jj = 0; jj < 8; jj++) o[jj] = t_lds[d][s8+jj];
    *(short8*)(vt + ((size_t)(b*H_ + h)*DH_ + d)*S_ + s0 + s8) = o;
  }
}

// ---------------- flash attention v7: DMA-staged K/V, PFAR far path ----------------
// grid = (bh=64, it=16) for XCD/L2 locality. K/V tiles DMA'd into unpadded
// XOR-swizzled LDS; p2c staged only on near tiles (5/16); far tiles read
// PFAR columns from global (L2). Far tiles: 2 barriers, near: 3.
#define PPS 68
__global__ __launch_bounds__(256, 4) void flash_kernel(const short* __restrict__ q,
                                                       const short* __restrict__ k,
                                                       const short* __restrict__ VT,
                                                       const short* __restrict__ c2p,
                                                       const short* __restrict__ p2c,
                                                       const short* __restrict__ PFAR,
                                                       const signed char* __restrict__ TAB,
                                                       short* __restrict__ ctx){
  __shared__ short k_lds[64*64];      // unpadded, XOR-swizzled (DMA dest)
  __shared__ short v_lds[64*64];      // VT tile [d][s], same scheme
  __shared__ short c2p_lds[64][72];
  __shared__ short pp_lds[64][PPS];   // near: p2c tile, then P; far: P only
  __shared__ signed char tab[2048];

  int bh = blockIdx.x, it = blockIdx.y;
  int b = bh >> 3, h = bh & 7;
  int i0 = it * 64;
  int tid = threadIdx.x, w = tid >> 6, lane = tid & 63, quad = lane >> 4, l16 = lane & 15;

  ((unsigned long long*)tab)[tid] = ((const unsigned long long*)TAB)[tid];  // 2048 B
  #pragma unroll
  for (int i = 0; i < 2; i++){
    int c = i*256 + tid;
    int r = c >> 3, cc = (c & 7) * 8;
    *(int4v*)&c2p_lds[r][cc] = *(const int4v*)(c2p + (size_t)(b*S_ + i0 + r)*D_ + h*DH_ + cc);
  }
  short8 qf0, qf1;
  {
    size_t row = (size_t)(b*S_ + i0 + w*16 + l16);
    qf0 = *(const short8*)(q + row*D_ + h*DH_ +      quad*8);
    qf1 = *(const short8*)(q + row*D_ + h*DH_ + 32 + quad*8);
  }
  const short* Kbase  = k   + (size_t)(b*S_)*D_ + h*DH_;
  const short* VTbase = VT  + (size_t)(b*H_ + h)*DH_*S_;
  const short* Pbase  = p2c + (size_t)(b*S_)*D_ + h*DH_;
  const short* Fbase  = PFAR + (size_t)bh*2048;

  // per-lane DMA sources (XOR swizzle baked in): row-group base must be %8==0
  int lr = lane >> 3, lc8 = ((lane & 7) ^ lr) * 8;
  const short* ksrc[2]; const short* vsrc[2];
  #pragma unroll
  for (int i = 0; i < 2; i++){
    int rr = w*16 + i*8 + lr;
    ksrc[i] = Kbase  + (size_t)rr*D_ + lc8;
    vsrc[i] = VTbase + (size_t)rr*S_ + lc8;
  }
  int sx = l16 & 7;
  int st_r = tid >> 3, st_c = (tid & 7) * 8;   // pp staging coords

  __syncthreads();

  float cpos[4], cneg[4];
  #pragma unroll
  for (int r = 0; r < 4; r++){
    int iloc = w*16 + quad*4 + r;
    cpos[r] = b2f(c2p_lds[iloc][63]);   // saturated idx, i-j >= 129
    cneg[r] = b2f(c2p_lds[iloc][0]);    // saturated idx, i-j <= -129
  }
  f32x4 o_acc[4] = {};
  float lrow[4] = {};                    // per-lane partial sums

  for (int jt = 0; jt < 16; jt++){
    int j0 = jt * 64;
    bool near = (jt >= it-2 && jt <= it+2);
    // prefetch p2c tile into VGPRs before the barrier (near only)
    int4v ppv0, ppv1;
    if (near){
      ppv0 = *(const int4v*)(Pbase + (size_t)(j0 + st_r     )*D_ + st_c);
      ppv1 = *(const int4v*)(Pbase + (size_t)(j0 + st_r + 32)*D_ + st_c);
    }
    __syncthreads();   // barrier A: prev tile's k/v/pp reads done
    #pragma unroll
    for (int i = 0; i < 2; i++){
      gl16(ksrc[i] + (size_t)j0*D_, &k_lds[(w*16 + i*8)*64]);
      gl16(vsrc[i] + j0,            &v_lds[(w*16 + i*8)*64]);
    }
    if (near){
      *(int4v*)&pp_lds[st_r     ][st_c] = ppv0;
      *(int4v*)&pp_lds[st_r + 32][st_c] = ppv1;
    }
    __syncthreads();   // barrier B: DMA drained + pp visible

    // ---- S = Q K^T (per wave: 16 rows x 64 cols), already scaled ----
    f32x4 sfr[4];
    #pragma unroll
    for (int nt = 0; nt < 4; nt++){
      int rowb = (nt*16 + l16) << 6;
      f32x4 a = {};
      a = mfma16(qf0, *(const short8*)&k_lds[rowb + ((quad^sx)<<3)], a);
      a = mfma16(qf1, *(const short8*)&k_lds[rowb + (((quad+4)^sx)<<3)], a);
      sfr[nt] = a;
    }
    // ---- P = exp(S + c2p + p2c); accumulate per-lane l partials ----
    float pval[4][4];
    if (near){
      #pragma unroll
      for (int nt = 0; nt < 4; nt++){
        int jloc = nt*16 + l16;
        #pragma unroll
        for (int r = 0; r < 4; r++){
          int iloc = w*16 + quad*4 + r;
          int idx  = tab[(i0 + iloc) - (j0 + jloc) + 1023];
          float p = __expf(sfr[nt][r] + b2f(c2p_lds[iloc][idx]) + b2f(pp_lds[jloc][idx]));
          pval[nt][r] = p;
          lrow[r] += p;
        }
      }
      __syncthreads();   // barrier C: pp (p2c) reads done before P overwrite
    } else {
      const float* cP = (jt < it) ? cpos : cneg;
      const short* fcol = Fbase + ((jt < it) ? 1024 : 0) + j0;
      #pragma unroll
      for (int nt = 0; nt < 4; nt++){
        float pv = b2f(fcol[nt*16 + l16]);
        #pragma unroll
        for (int r = 0; r < 4; r++){
          float p = __expf(sfr[nt][r] + cP[r] + pv);
          pval[nt][r] = p;
          lrow[r] += p;
        }
      }
      // no barrier: pp band is wave-private in far tiles
    }

    // ---- P: C-layout -> A-layout via wave-private pp_lds band ----
    #pragma unroll
    for (int nt = 0; nt < 4; nt++)
      #pragma unroll
      for (int r = 0; r < 4; r++)
        pp_lds[w*16 + quad*4 + r][nt*16 + l16] = f2b(pval[nt][r]);
    short8 pf0 = *(const short8*)&pp_lds[w*16 + l16][     quad*8];
    short8 pf1 = *(const short8*)&pp_lds[w*16 + l16][32 + quad*8];
    // ---- O += P V ----
    #pragma unroll
    for (int nt = 0; nt < 4; nt++){
      int rowb = (nt*16 + l16) << 6;
      o_acc[nt] = mfma16(pf0, *(const short8*)&v_lds[rowb + ((quad^sx)<<3)], o_acc[nt]);
      o_acc[nt] = mfma16(pf1, *(const short8*)&v_lds[rowb + (((quad+4)^sx)<<3)], o_acc[nt]);
    }
  }
  // final row-sum reduction over the 16 lanes of each quad group
  #pragma unroll
  for (int r = 0; r < 4; r++){
    #pragma unroll
    for (int off = 8; off; off >>= 1) lrow[r] += __shfl_xor(lrow[r], off);
  }
  #pragma unroll
  for (int nt = 0; nt < 4; nt++)
    #pragma unroll
    for (int r = 0; r < 4; r++){
      size_t row = (size_t)(b*S_ + i0 + w*16 + quad*4 + r);
      ctx[row*D_ + h*DH_ + nt*16 + l16] = f2b(o_acc[nt][r] / lrow[r]);
    }
}

// ---------------- workspace layout (bytes) — high-water 55,511,040 (~52.9 MB) ----------------
static const size_t OFF_XN   = 0;           // bf16 8192x512  (alias: VT)
static const size_t OFF_Q    = 8388608;     // bf16 8192x512  (alias: FFH lo)
static const size_t OFF_K    = 16777216;    // bf16 8192x512  (alias: FFH hi)
static const size_t OFF_V    = 25165824;    // bf16 8192x512  (alias: CTX)
static const size_t OFF_C2P  = 33554432;    // bf16 8192x512  (alias: DWS)
static const size_t OFF_P2C  = 41943040;    // bf16 8192x512
static const size_t OFF_WPW  = 50331648;    // bf16 512x512
static const size_t OFF_WQ   = 50855936;    // WQ/WK/WV contiguous = [1536,512]
static const size_t OFF_WK   = 51380224;
static const size_t OFF_WV   = 51904512;
static const size_t OFF_WO   = 52428800;
static const size_t OFF_W1   = 52953088;    // bf16 1024x512
static const size_t OFF_W2   = 54001664;    // bf16 512x1024
static const size_t OFF_REL  = 55050240;    // bf16 64x512
static const size_t OFF_POSK = 55115776;    // bf16 64x512
static const size_t OFF_POSQ = 55181312;    // bf16 64x512
static const size_t OFF_TAB  = 55246848;    // int8 2048
static const size_t OFF_PFAR = 55248896;    // bf16 64*2*1024 = 256 KB

extern "C" void kernel_launch(void* const* d_in, const int* in_sizes, int n_in,
                              void* d_out, int out_size, void* d_ws, size_t ws_size,
                              hipStream_t stream){
  const float* x    = (const float*)d_in[0];
  const float* ln1g = (const float*)d_in[1];
  const float* ln1b = (const float*)d_in[2];
  const float* dww  = (const float*)d_in[3];
  const float* dwb  = (const float*)d_in[4];
  const float* pww  = (const float*)d_in[5];
  const float* pwb  = (const float*)d_in[6];
  const float* ln2g = (const float*)d_in[7];
  const float* ln2b = (const float*)d_in[8];
  const float* qw   = (const float*)d_in[9];
  const float* qb   = (const float*)d_in[10];
  const float* kw   = (const float*)d_in[11];
  const float* kb   = (const float*)d_in[12];
  const float* vw   = (const float*)d_in[13];
  const float* vb   = (const float*)d_in[14];
  const float* ow   = (const float*)d_in[15];
  const float* ob   = (const float*)d_in[16];
  const float* rel  = (const float*)d_in[17];
  const float* ln3g = (const float*)d_in[18];
  const float* ln3b = (const float*)d_in[19];
  const float* w1   = (const float*)d_in[20];
  const float* b1   = (const float*)d_in[21];
  const float* w2   = (const float*)d_in[22];
  const float* b2   = (const float*)d_in[23];
  float* out = (float*)d_out;
  char* ws = (char*)d_ws;

  short* XN   = (short*)(ws + OFF_XN);
  short* Q    = (short*)(ws + OFF_Q);
  short* Kb_  = (short*)(ws + OFF_K);
  short* V    = (short*)(ws + OFF_V);
  short* C2P  = (short*)(ws + OFF_C2P);
  short* P2C  = (short*)(ws + OFF_P2C);
  short* WPW  = (short*)(ws + OFF_WPW);
  short* WQ   = (short*)(ws + OFF_WQ);
  short* WK   = (short*)(ws + OFF_WK);
  short* WV   = (short*)(ws + OFF_WV);
  short* WO   = (short*)(ws + OFF_WO);
  short* W1B  = (short*)(ws + OFF_W1);
  short* W2B  = (short*)(ws + OFF_W2);
  short* RELB = (short*)(ws + OFF_REL);
  short* POSK = (short*)(ws + OFF_POSK);
  short* POSQ = (short*)(ws + OFF_POSQ);
  signed char* TAB = (signed char*)(ws + OFF_TAB);
  short* PFAR = (short*)(ws + OFF_PFAR);
  short* DWS  = C2P;     // alias
  short* VT   = XN;      // alias
  short* CTX  = V;       // alias
  short* FFH  = Q;       // alias (16 MB over Q+K)

  // fused weight conversions + bucket table
  F2B8 fa;
  fa.s[0]=pww; fa.d[0]=WPW; fa.n[0]=262144;
  fa.s[1]=qw;  fa.d[1]=WQ;  fa.n[1]=262144;
  fa.s[2]=kw;  fa.d[2]=WK;  fa.n[2]=262144;
  fa.s[3]=vw;  fa.d[3]=WV;  fa.n[3]=262144;
  fa.s[4]=ow;  fa.d[4]=WO;  fa.n[4]=262144;
  fa.s[5]=w1;  fa.d[5]=W1B; fa.n[5]=524288;
  fa.s[6]=w2;  fa.d[6]=W2B; fa.n[6]=524288;
  fa.s[7]=rel; fa.d[7]=RELB;fa.n[7]=32768;
  f2b8_kernel<<<dim3(512,8), 256, 0, stream>>>(fa);
  tab_kernel<<<8, 256, 0, stream>>>(TAB);

  // conv block: out = x + pw(silu(dwconv(ln1(x))))
  ln_kernel<<<BS_, 128, 0, stream>>>(x, ln1g, ln1b, XN);
  dwconv_kernel<<<2048, 256, 0, stream>>>(XN, dww, dwb, DWS);
  gemm_gl<false,true,true,false><<<dim3(64,8), 256, 0, stream>>>(
      DWS, WPW, pwb, x, out, nullptr, BS_, 512, 512);

  // attention block
  ln_kernel<<<BS_, 128, 0, stream>>>(out, ln2g, ln2b, XN);
  gemm_qkv<<<dim3(64,24), 256, 0, stream>>>(
      XN, WQ, qb, kb, vb, Q, Kb_, V, BS_, 512);
  gemm_pos<<<8, 256, 0, stream>>>(RELB, WK, kb, POSK, 1.f,    512, 512);
  gemm_pos<<<8, 256, 0, stream>>>(RELB, WQ, qb, POSQ, SCALE_, 512, 512);
  posbias_kernel<<<dim3(128,8), 256, 0, stream>>>(Q, Kb_, POSK, POSQ, C2P, P2C, PFAR);
  vtrans_kernel<<<dim3(16,8,8), 256, 0, stream>>>(V, VT);
  flash_kernel<<<dim3(64,16), 256, 0, stream>>>(Q, Kb_, VT, C2P, P2C, PFAR, TAB, CTX);
  gemm_gl<false,true,true,false><<<dim3(64,8), 256, 0, stream>>>(
      CTX, WO, ob, out, out, nullptr, BS_, 512, 512);

  // FFN block: out += w2 @ silu(w1 @ ln3(out))
  ln_kernel<<<BS_, 128, 0, stream>>>(out, ln3g, ln3b, XN);
  gemm_gl<true,false,false,true><<<dim3(64,16), 256, 0, stream>>>(
      XN, W1B, b1, nullptr, nullptr, FFH, BS_, 1024, 512);
  gemm_gl<false,true,true,false><<<dim3(64,8), 256, 0, stream>>>(
      FFH, W2B, b2, out, out, nullptr, BS_, 512, 1024);
}

// Round 8
// 321.592 us; speedup vs baseline: 1.6000x; 1.0051x over previous
//
#include <hip/hip_runtime.h>
#include <hip/hip_bf16.h>
#include <math.h>

// MEGConformerLayer: conv block + DeBERTa-v2 attention + FFN, all bf16 MFMA.
// B=8 S=1024 D=512 H=8 DH=64 K=3 FF=1024 BUCKETS=32 SPAN=32
// R8: flash v8 — operand-swapped S^T = K*Q^T so exp'd scores are ALREADY in
// the A-layout of mfma_16x16x16_bf16: PV runs from registers, P LDS
// round-trip deleted (fallback to R7 kernel if builtin missing).
// qkv/ffn1 -> 128x128 tiles (64x64 per wave, 0.5 ds_read/MFMA).

#define B_  8
#define S_  1024
#define D_  512
#define H_  8
#define DH_ 64
#define FF_ 1024
#define BS_ (B_*S_)   // 8192
#define SCALE_ 0.07216878364f   // 1/sqrt(DH*3)

typedef __attribute__((ext_vector_type(8))) short  short8;
typedef __attribute__((ext_vector_type(4))) short  short4v;
typedef __attribute__((ext_vector_type(4))) float  f32x4;
typedef __attribute__((ext_vector_type(4))) int    int4v;

#if __has_builtin(__builtin_amdgcn_mfma_f32_16x16x16bf16_1k)
#define HAS_K16 1
static __device__ __forceinline__ f32x4 mfma_k16(short4v a, short4v b, f32x4 c){
  return __builtin_amdgcn_mfma_f32_16x16x16bf16_1k(a, b, c, 0, 0, 0);
}
#else
#define HAS_K16 0
#endif

static __device__ __forceinline__ float b2f(short u){
  union { int i; float f; } cv; cv.i = ((int)(unsigned short)u) << 16; return cv.f;
}
static __device__ __forceinline__ short f2b(float f){
  union { float f; unsigned u; } cv; cv.f = f;
  unsigned r = cv.u + 0x7FFFu + ((cv.u >> 16) & 1u);  // RNE
  return (short)(r >> 16);
}
static __device__ __forceinline__ float silu_f(float x){
  return x / (1.f + __expf(-x));
}
static __device__ __forceinline__ f32x4 mfma16(short8 a, short8 b, f32x4 c){
  return __builtin_amdgcn_mfma_f32_16x16x32_bf16(a, b, c, 0, 0, 0);
}
// async global->LDS, 16B/lane; dest = wave-uniform base + lane*16
static __device__ __forceinline__ void gl16(const void* g, void* l){
  __builtin_amdgcn_global_load_lds((const __attribute__((address_space(1))) void*)g,
                                   (__attribute__((address_space(3))) void*)l, 16, 0, 0);
}

// ---------------- fused fp32 -> bf16 weight convert (8 segments, 1 launch) ----------------
struct F2B8 { const float* s[8]; short* d[8]; int n[8]; };
__global__ __launch_bounds__(256) void f2b8_kernel(F2B8 a){
  int seg = blockIdx.y;
  int i = (blockIdx.x*256 + threadIdx.x)*4;
  if (i >= a.n[seg]) return;
  float4 v = *(const float4*)(a.s[seg] + i);
  short4v o; o.x = f2b(v.x); o.y = f2b(v.y); o.z = f2b(v.z); o.w = f2b(v.w);
  *(short4v*)(a.d[seg] + i) = o;
}

// ---------------- DeBERTa log-bucket index table: delta=i-j in [-1023,1024] ----------------
__global__ __launch_bounds__(256) void tab_kernel(signed char* __restrict__ tab){
  int t = blockIdx.x*256 + threadIdx.x;
  if (t >= 2048) return;
  int d = t - 1023;
  int ad = d < 0 ? -d : d;
  int bkt;
  if (ad <= 16) bkt = d;
  else {
    const float inv_log = 15.f / logf(7.9375f);   // (mid-1)/log((MAX_REL-1)/mid)
    float lp = ceilf(logf((float)ad * (1.f/16.f)) * inv_log) + 16.f;
    int ilp = (int)lp;
    bkt = (d > 0) ? ilp : -ilp;
  }
  int idx = bkt + 32;
  idx = idx < 0 ? 0 : (idx > 63 ? 63 : idx);
  tab[t] = (signed char)idx;
}

// ---------------- LayerNorm (rows of 512), fp32 in -> bf16 out ----------------
__global__ __launch_bounds__(128) void ln_kernel(const float* __restrict__ x,
                                                 const float* __restrict__ g,
                                                 const float* __restrict__ bb,
                                                 short* __restrict__ out){
  int row = blockIdx.x;
  int tid = threadIdx.x;               // 128 threads * float4 = 512
  float4 v = ((const float4*)(x + (size_t)row*D_))[tid];
  float s  = v.x + v.y + v.z + v.w;
  float ss = v.x*v.x + v.y*v.y + v.z*v.z + v.w*v.w;
  #pragma unroll
  for (int off = 32; off; off >>= 1){ s += __shfl_down(s, off); ss += __shfl_down(ss, off); }
  __shared__ float red[4];
  if ((tid & 63) == 0){ red[tid>>6] = s; red[2 + (tid>>6)] = ss; }
  __syncthreads();
  float S  = red[0] + red[1];
  float SS = red[2] + red[3];
  float m   = S * (1.f/D_);
  float var = SS * (1.f/D_) - m*m;
  float rs  = rsqrtf(var + 1e-5f);
  float4 gv = ((const float4*)g)[tid];
  float4 bv = ((const float4*)bb)[tid];
  short4v o;
  o.x = f2b((v.x - m)*rs*gv.x + bv.x);
  o.y = f2b((v.y - m)*rs*gv.y + bv.y);
  o.z = f2b((v.z - m)*rs*gv.z + bv.z);
  o.w = f2b((v.w - m)*rs*gv.w + bv.w);
  *(short4v*)(out + (size_t)row*D_ + tid*4) = o;
}

// ---------------- depthwise conv (K=3, pad 1, per-seq) + SiLU, bf16->bf16 ----------------
__global__ __launch_bounds__(256) void dwconv_kernel(const short* __restrict__ xn,
                                                     const float* __restrict__ w,   // [D,1,3]
                                                     const float* __restrict__ bias,
                                                     short* __restrict__ out){
  int idx = blockIdx.x*256 + threadIdx.x;   // BS_*64 threads, 8 channels each
  int bs  = idx >> 6;
  int d8  = (idx & 63) << 3;
  int s   = bs & (S_-1);
  const short* base = xn + (size_t)bs*D_ + d8;
  short8 z = {};
  short8 xm = (s > 0)     ? *(const short8*)(base - D_) : z;
  short8 xc =               *(const short8*)(base);
  short8 xp = (s < S_-1)  ? *(const short8*)(base + D_) : z;
  short8 o;
  #pragma unroll
  for (int i = 0; i < 8; i++){
    int d = d8 + i;
    float acc = bias[d] + b2f(xm[i])*w[d*3+0] + b2f(xc[i])*w[d*3+1] + b2f(xp[i])*w[d*3+2];
    o[i] = f2b(silu_f(acc));
  }
  *(short8*)(out + (size_t)bs*D_ + d8) = o;
}

// ====== GEMM core: 128Mx64N, BK=64, double-buffered DMA, single barrier/step ======
#define GEMM_GL_CORE(AP, WP, KK)                                               \
  __shared__ short a_lds[2][128*64];                                           \
  __shared__ short b_lds[2][64*64];                                            \
  int tid = threadIdx.x;                                                       \
  int w = tid >> 6, lane = tid & 63, quad = lane >> 4, l16 = lane & 15;        \
  int wm = (w >> 1) * 64, wn = (w & 1) * 32;                                   \
  int m0 = blockIdx.x * 128, n0 = blockIdx.y * 64;                             \
  int lr = lane >> 3, lc8 = ((lane & 7) ^ lr) * 8;                             \
  const short* asrc[4]; const short* bsrc[2];                                  \
  _Pragma("unroll")                                                            \
  for (int i = 0; i < 4; i++)                                                  \
    asrc[i] = AP + (size_t)(m0 + w*32 + i*8 + lr)*KK + lc8;                    \
  _Pragma("unroll")                                                            \
  for (int i = 0; i < 2; i++)                                                  \
    bsrc[i] = WP + (size_t)(n0 + w*16 + i*8 + lr)*KK + lc8;                    \
  f32x4 acc[4][2] = {};                                                        \
  int sx = l16 & 7;                                                            \
  _Pragma("unroll")                                                            \
  for (int i = 0; i < 4; i++) gl16(asrc[i], &a_lds[0][(w*32 + i*8)*64]);       \
  _Pragma("unroll")                                                            \
  for (int i = 0; i < 2; i++) gl16(bsrc[i], &b_lds[0][(w*16 + i*8)*64]);       \
  int cur = 0;                                                                 \
  for (int kk = 0; kk < KK; kk += 64){                                         \
    __syncthreads();                                                           \
    if (kk + 64 < KK){                                                         \
      _Pragma("unroll")                                                        \
      for (int i = 0; i < 4; i++)                                              \
        gl16(asrc[i] + kk + 64, &a_lds[cur^1][(w*32 + i*8)*64]);               \
      _Pragma("unroll")                                                        \
      for (int i = 0; i < 2; i++)                                              \
        gl16(bsrc[i] + kk + 64, &b_lds[cur^1][(w*16 + i*8)*64]);               \
    }                                                                          \
    _Pragma("unroll")                                                          \
    for (int ks = 0; ks < 2; ks++){                                            \
      short8 b0 = *(const short8*)&b_lds[cur][((wn      + l16)<<6) + (((ks*4+quad)^sx)<<3)]; \
      short8 b1 = *(const short8*)&b_lds[cur][((wn + 16 + l16)<<6) + (((ks*4+quad)^sx)<<3)]; \
      _Pragma("unroll")                                                        \
      for (int mt = 0; mt < 4; mt++){                                          \
        short8 a = *(const short8*)&a_lds[cur][((wm + mt*16 + l16)<<6) + (((ks*4+quad)^sx)<<3)]; \
        acc[mt][0] = mfma16(a, b0, acc[mt][0]);                                \
        acc[mt][1] = mfma16(a, b1, acc[mt][1]);                                \
      }                                                                        \
    }                                                                          \
    cur ^= 1;                                                                  \
  }

template<bool SILU, bool RES, bool OF32, bool OBF>
__global__ __launch_bounds__(256) void gemm_gl(const short* __restrict__ A,
                                               const short* __restrict__ W,
                                               const float* __restrict__ bias,
                                               const float* res,
                                               float* of32,
                                               short* __restrict__ obf,
                                               int M, int N, int K){
  GEMM_GL_CORE(A, W, K)
  #pragma unroll
  for (int mt = 0; mt < 4; mt++)
    #pragma unroll
    for (int nt = 0; nt < 2; nt++)
      #pragma unroll
      for (int r = 0; r < 4; r++){
        int row = m0 + wm + mt*16 + quad*4 + r;
        int col = n0 + wn + nt*16 + l16;
        float val = acc[mt][nt][r] + bias[col];
        if (SILU) val = silu_f(val);
        if (RES)  val += res[(size_t)row*N + col];
        if (OF32) of32[(size_t)row*N + col] = val;
        if (OBF)  obf[(size_t)row*N + col] = f2b(val);
      }
}

// ====== GEMM core2: 128Mx128N, BK=64, wave tile 64x64 (0.5 ds_read/MFMA) ======
#define GEMM_GL2_CORE(AP, WP, KK)                                              \
  __shared__ short a_lds[2][128*64];                                           \
  __shared__ short b_lds[2][128*64];                                           \
  int tid = threadIdx.x;                                                       \
  int w = tid >> 6, lane = tid & 63, quad = lane >> 4, l16 = lane & 15;        \
  int wm = (w >> 1) * 64, wn = (w & 1) * 64;                                   \
  int m0 = blockIdx.x * 128, n0 = blockIdx.y * 128;                            \
  int lr = lane >> 3, lc8 = ((lane & 7) ^ lr) * 8;                             \
  const short* asrc[4]; const short* bsrc[4];                                  \
  _Pragma("unroll")                                                            \
  for (int i = 0; i < 4; i++){                                                 \
    asrc[i] = AP + (size_t)(m0 + w*32 + i*8 + lr)*KK + lc8;                    \
    bsrc[i] = WP + (size_t)(n0 + w*32 + i*8 + lr)*KK + lc8;                    \
  }                                                                            \
  f32x4 acc[4][4] = {};                                                        \
  int sx = l16 & 7;                                                            \
  _Pragma("unroll")                                                            \
  for (int i = 0; i < 4; i++){                                                 \
    gl16(asrc[i], &a_lds[0][(w*32 + i*8)*64]);                                 \
    gl16(bsrc[i], &b_lds[0][(w*32 + i*8)*64]);                                 \
  }                                                                            \
  int cur = 0;                                                                 \
  for (int kk = 0; kk < KK; kk += 64){                                         \
    __syncthreads();                                                           \
    if (kk + 64 < KK){                                                         \
      _Pragma("unroll")                                                        \
      for (int i = 0; i < 4; i++){                                             \
        gl16(asrc[i] + kk + 64, &a_lds[cur^1][(w*32 + i*8)*64]);               \
        gl16(bsrc[i] + kk + 64, &b_lds[cur^1][(w*32 + i*8)*64]);               \
      }                                                                        \
    }                                                                          \
    _Pragma("unroll")                                                          \
    for (int ks = 0; ks < 2; ks++){                                            \
      short8 bfr[4];                                                           \
      _Pragma("unroll")                                                        \
      for (int nt = 0; nt < 4; nt++)                                           \
        bfr[nt] = *(const short8*)&b_lds[cur][((wn + nt*16 + l16)<<6) + (((ks*4+quad)^sx)<<3)]; \
      _Pragma("unroll")                                                        \
      for (int mt = 0; mt < 4; mt++){                                          \
        short8 a = *(const short8*)&a_lds[cur][((wm + mt*16 + l16)<<6) + (((ks*4+quad)^sx)<<3)]; \
        _Pragma("unroll")                                                      \
        for (int nt = 0; nt < 4; nt++)                                         \
          acc[mt][nt] = mfma16(a, bfr[nt], acc[mt][nt]);                       \
      }                                                                        \
    }                                                                          \
    cur ^= 1;                                                                  \
  }

template<bool SILU, bool OBF>
__global__ __launch_bounds__(256) void gemm_gl2(const short* __restrict__ A,
                                                const short* __restrict__ W,
                                                const float* __restrict__ bias,
                                                short* __restrict__ obf,
                                                int M, int N, int K){
  GEMM_GL2_CORE(A, W, K)
  #pragma unroll
  for (int mt = 0; mt < 4; mt++)
    #pragma unroll
    for (int nt = 0; nt < 4; nt++)
      #pragma unroll
      for (int r = 0; r < 4; r++){
        int row = m0 + wm + mt*16 + quad*4 + r;
        int col = n0 + wn + nt*16 + l16;
        float val = acc[mt][nt][r] + bias[col];
        if (SILU) val = silu_f(val);
        if (OBF)  obf[(size_t)row*N + col] = f2b(val);
      }
}

// fused QKV projection on the 128x128 core: W = [WQ;WK;WV] (1536x512).
__global__ __launch_bounds__(256) void gemm_qkv2(const short* __restrict__ A,
                                                 const short* __restrict__ W,
                                                 const float* __restrict__ qb,
                                                 const float* __restrict__ kb,
                                                 const float* __restrict__ vb,
                                                 short* __restrict__ Qo,
                                                 short* __restrict__ Ko,
                                                 short* __restrict__ Vo,
                                                 int M, int K){
  GEMM_GL2_CORE(A, W, K)
  int colb = n0 + wn;
  int sel = colb >> 9;                       // uniform per (block, wn) tile
  const float* bp = sel == 0 ? qb : (sel == 1 ? kb : vb);
  short* dp = sel == 0 ? Qo : (sel == 1 ? Ko : Vo);
  float mult = sel == 0 ? SCALE_ : 1.f;
  #pragma unroll
  for (int mt = 0; mt < 4; mt++)
    #pragma unroll
    for (int nt = 0; nt < 4; nt++)
      #pragma unroll
      for (int r = 0; r < 4; r++){
        int row = m0 + wm + mt*16 + quad*4 + r;
        int col = (colb + nt*16 + l16) & 511;
        float val = (acc[mt][nt][r] + bp[col]) * mult;
        dp[(size_t)row*D_ + col] = f2b(val);
      }
}

// ---------------- GEMM 64x64 (two tiny M=64 pos-projection gemms) ----------------
__global__ __launch_bounds__(256) void gemm_pos(const short* __restrict__ A,
                                                const short* __restrict__ W,
                                                const float* __restrict__ bias,
                                                short* __restrict__ obf,
                                                float mult, int N, int K){
  __shared__ short a_lds[64][72];
  __shared__ short b_lds[64][72];
  int tid = threadIdx.x;
  int w = tid >> 6, lane = tid & 63, quad = lane >> 4, l16 = lane & 15;
  int wm = (w >> 1) * 32, wn = (w & 1) * 32;
  int m0 = 0, n0 = blockIdx.x * 64;
  int r0 = tid >> 3, c0 = (tid & 7) * 8;
  int r1 = r0 + 32;
  f32x4 acc[2][2] = {};
  for (int kk = 0; kk < K; kk += 64){
    *(int4v*)&a_lds[r0][c0] = *(const int4v*)(A + (size_t)(m0+r0)*K + kk + c0);
    *(int4v*)&a_lds[r1][c0] = *(const int4v*)(A + (size_t)(m0+r1)*K + kk + c0);
    *(int4v*)&b_lds[r0][c0] = *(const int4v*)(W + (size_t)(n0+r0)*K + kk + c0);
    *(int4v*)&b_lds[r1][c0] = *(const int4v*)(W + (size_t)(n0+r1)*K + kk + c0);
    __syncthreads();
    #pragma unroll
    for (int ks = 0; ks < 2; ks++){
      short8 a0 = *(const short8*)&a_lds[wm      + l16][ks*32 + quad*8];
      short8 a1 = *(const short8*)&a_lds[wm + 16 + l16][ks*32 + quad*8];
      short8 b0 = *(const short8*)&b_lds[wn      + l16][ks*32 + quad*8];
      short8 b1 = *(const short8*)&b_lds[wn + 16 + l16][ks*32 + quad*8];
      acc[0][0] = mfma16(a0, b0, acc[0][0]);
      acc[0][1] = mfma16(a0, b1, acc[0][1]);
      acc[1][0] = mfma16(a1, b0, acc[1][0]);
      acc[1][1] = mfma16(a1, b1, acc[1][1]);
    }
    __syncthreads();
  }
  #pragma unroll
  for (int mt = 0; mt < 2; mt++)
    #pragma unroll
    for (int nt = 0; nt < 2; nt++)
      #pragma unroll
      for (int r = 0; r < 4; r++){
        int row = m0 + wm + mt*16 + quad*4 + r;
        int col = n0 + wn + nt*16 + l16;
        obf[(size_t)row*N + col] = f2b((acc[mt][nt][r] + bias[col]) * mult);
      }
}

// ---------------- c2p/p2c position-bias batched GEMM (+ PFAR columns) ----------------
__global__ __launch_bounds__(256) void posbias_kernel(const short* __restrict__ q,
                                                      const short* __restrict__ k,
                                                      const short* __restrict__ posk,
                                                      const short* __restrict__ posq,
                                                      short* __restrict__ c2p,
                                                      short* __restrict__ p2c,
                                                      short* __restrict__ pfar){
  int bsT = blockIdx.x;          // 128 tiles of 64 rows
  int h   = blockIdx.y;
  int tid = threadIdx.x, w = tid >> 6, lane = tid & 63, quad = lane >> 4, l16 = lane & 15;
  int row_a = bsT*64 + w*16 + l16;
  f32x4 accc[4] = {}, accp[4] = {};
  #pragma unroll
  for (int ks = 0; ks < 2; ks++){
    short8 aq = *(const short8*)(q + (size_t)row_a*D_ + h*DH_ + ks*32 + quad*8);
    short8 ak = *(const short8*)(k + (size_t)row_a*D_ + h*DH_ + ks*32 + quad*8);
    #pragma unroll
    for (int nt = 0; nt < 4; nt++){
      short8 bk = *(const short8*)(posk + (size_t)(nt*16+l16)*D_ + h*DH_ + ks*32 + quad*8);
      short8 bq = *(const short8*)(posq + (size_t)(nt*16+l16)*D_ + h*DH_ + ks*32 + quad*8);
      accc[nt] = mfma16(aq, bk, accc[nt]);
      accp[nt] = mfma16(ak, bq, accp[nt]);
    }
  }
  #pragma unroll
  for (int nt = 0; nt < 4; nt++)
    #pragma unroll
    for (int r = 0; r < 4; r++){
      int row = bsT*64 + w*16 + quad*4 + r;
      int col = h*DH_ + nt*16 + l16;
      short pv = f2b(accp[nt][r]);
      c2p[(size_t)row*D_ + col] = f2b(accc[nt][r]);
      p2c[(size_t)row*D_ + col] = pv;
      int cin = nt*16 + l16;          // column within head, 0..63
      if (cin == 0 || cin == 63){
        int b  = row >> 10, s = row & 1023;
        int bh = b*H_ + h;
        pfar[(size_t)bh*2048 + (cin ? 1024 : 0) + s] = pv;
      }
    }
}

// ---------------- V -> VT[B,H,DH,S] pre-transpose (65-pad: 2-way conflicts = free) ------
__global__ __launch_bounds__(256) void vtrans_kernel(const short* __restrict__ v,
                                                     short* __restrict__ vt){
  __shared__ short t_lds[64][65];
  int st = blockIdx.x, h = blockIdx.y, b = blockIdx.z;
  int s0 = st*64;
  int tid = threadIdx.x;
  #pragma unroll
  for (int i = 0; i < 2; i++){
    int c = i*256 + tid;
    int s = c >> 3, d8 = (c & 7) * 8;
    short8 vv = *(const short8*)(v + (size_t)(b*S_ + s0 + s)*D_ + h*DH_ + d8);
    #pragma unroll
    for (int jj = 0; jj < 8; jj++) t_lds[d8+jj][s] = vv[jj];
  }
  __syncthreads();
  #pragma unroll
  for (int i = 0; i < 2; i++){
    int c = i*256 + tid;
    int d = c >> 3, s8 = (c & 7) * 8;
    short8 o;
    #pragma unroll
    for (int jj = 0; jj < 8; jj++) o[jj] = t_lds[d][s8+jj];
    *(short8*)(vt + ((size_t)(b*H_ + h)*DH_ + d)*S_ + s0 + s8) = o;
  }
}

#if HAS_K16
// ---------------- flash attention v8: operand-swapped S^T, register PV ----------------
// S^T = K*Q^T: C-frag (col=lane=i, row=quad*4+r=j) == A-frag of 16x16x16 MFMA
// (m=lane=i, k=quad*4+r=j) -> exp'd P feeds PV straight from registers.
// V consumed as B-frags (b64 from XOR-swizzled v_lds). 2 barriers/tile.
__global__ __launch_bounds__(256, 4) void flash_kernel(const short* __restrict__ q,
                                                       const short* __restrict__ k,
                                                       const short* __restrict__ VT,
                                                       const short* __restrict__ c2p,
                                                       const short* __restrict__ p2c,
                                                       const short* __restrict__ PFAR,
                                                       const signed char* __restrict__ TAB,
                                                       short* __restrict__ ctx){
  __shared__ short k_lds[64*64];      // unpadded, XOR-swizzled (DMA dest)
  __shared__ short v_lds[64*64];      // VT tile [d][s], same scheme
  __shared__ short c2p_lds[64][72];
  __shared__ short pp_lds[64][72];    // p2c tile (near tiles only)
  __shared__ signed char tab[2048];

  int bh = blockIdx.x, it = blockIdx.y;
  int b = bh >> 3, h = bh & 7;
  int i0 = it * 64;
  int tid = threadIdx.x, w = tid >> 6, lane = tid & 63, quad = lane >> 4, l16 = lane & 15;

  ((unsigned long long*)tab)[tid] = ((const unsigned long long*)TAB)[tid];  // 2048 B
  #pragma unroll
  for (int i = 0; i < 2; i++){
    int c = i*256 + tid;
    int r = c >> 3, cc = (c & 7) * 8;
    *(int4v*)&c2p_lds[r][cc] = *(const int4v*)(c2p + (size_t)(b*S_ + i0 + r)*D_ + h*DH_ + cc);
  }
  short8 qf0, qf1;   // Q as B-operand: lane=n=i, k=quad*8+d — same read as before
  {
    size_t row = (size_t)(b*S_ + i0 + w*16 + l16);
    qf0 = *(const short8*)(q + row*D_ + h*DH_ +      quad*8);
    qf1 = *(const short8*)(q + row*D_ + h*DH_ + 32 + quad*8);
  }
  const short* Kbase  = k   + (size_t)(b*S_)*D_ + h*DH_;
  const short* VTbase = VT  + (size_t)(b*H_ + h)*DH_*S_;
  const short* Pbase  = p2c + (size_t)(b*S_)*D_ + h*DH_;
  const short* Fbase  = PFAR + (size_t)bh*2048;

  int lr = lane >> 3, lc8 = ((lane & 7) ^ lr) * 8;
  const short* ksrc[2]; const short* vsrc[2];
  #pragma unroll
  for (int i = 0; i < 2; i++){
    int rr = w*16 + i*8 + lr;
    ksrc[i] = Kbase  + (size_t)rr*D_ + lc8;
    vsrc[i] = VTbase + (size_t)rr*S_ + lc8;
  }
  int sx = l16 & 7;
  int st_r = tid >> 3, st_c = (tid & 7) * 8;

  __syncthreads();
  int myi = i0 + w*16 + l16;                    // this lane's softmax row
  float cpos = b2f(c2p_lds[w*16 + l16][63]);    // saturated, i-j >= 129
  float cneg = b2f(c2p_lds[w*16 + l16][0]);     // saturated, i-j <= -129
  f32x4 o_acc[4] = {};
  float lrow = 0.f;

  for (int jt = 0; jt < 16; jt++){
    int j0 = jt * 64;
    bool near = (jt >= it-2 && jt <= it+2);
    int4v ppv0, ppv1;
    if (near){
      ppv0 = *(const int4v*)(Pbase + (size_t)(j0 + st_r     )*D_ + st_c);
      ppv1 = *(const int4v*)(Pbase + (size_t)(j0 + st_r + 32)*D_ + st_c);
    }
    __syncthreads();   // barrier A: prev tile reads done
    #pragma unroll
    for (int i = 0; i < 2; i++){
      gl16(ksrc[i] + (size_t)j0*D_, &k_lds[(w*16 + i*8)*64]);
      gl16(vsrc[i] + j0,            &v_lds[(w*16 + i*8)*64]);
    }
    if (near){
      *(int4v*)&pp_lds[st_r     ][st_c] = ppv0;
      *(int4v*)&pp_lds[st_r + 32][st_c] = ppv1;
    }
    __syncthreads();   // barrier B: DMA drained + pp visible

    // ---- S^T = K Q^T per 16-row j-subtile (K as A-operand) ----
    f32x4 sfr[4];
    #pragma unroll
    for (int js = 0; js < 4; js++){
      int rowb = (js*16 + l16) << 6;
      f32x4 a = {};
      a = mfma16(*(const short8*)&k_lds[rowb + ((quad^sx)<<3)],     qf0, a);
      a = mfma16(*(const short8*)&k_lds[rowb + (((quad+4)^sx)<<3)], qf1, a);
      sfr[js] = a;
    }
    // ---- P = exp(S + c2p + p2c), straight into A-frags; l partials ----
    short4v pb[4];
    if (near){
      #pragma unroll
      for (int js = 0; js < 4; js++){
        #pragma unroll
        for (int r = 0; r < 4; r++){
          int j = j0 + js*16 + quad*4 + r;
          int idx = tab[myi - j + 1023];
          float p = __expf(sfr[js][r] + b2f(c2p_lds[w*16 + l16][idx])
                                      + b2f(pp_lds[js*16 + quad*4 + r][idx]));
          lrow += p;
          pb[js][r] = f2b(p);
        }
      }
    } else {
      float cP = (jt < it) ? cpos : cneg;
      const short* fcol = Fbase + ((jt < it) ? 1024 : 0) + j0;
      #pragma unroll
      for (int js = 0; js < 4; js++){
        short4v pv4 = *(const short4v*)(fcol + js*16 + quad*4);
        #pragma unroll
        for (int r = 0; r < 4; r++){
          float p = __expf(sfr[js][r] + cP + b2f(pv4[r]));
          lrow += p;
          pb[js][r] = f2b(p);
        }
      }
    }
    // ---- O += P V : A = pb (registers), B = V b64 frags ----
    #pragma unroll
    for (int js = 0; js < 4; js++){
      #pragma unroll
      for (int nt = 0; nt < 4; nt++){
        int row = nt*16 + l16;
        int chunk = (2*js + (quad >> 1)) ^ (row & 7);
        const short* vp = &v_lds[(row << 6) + (chunk << 3) + ((quad & 1) << 2)];
        o_acc[nt] = mfma_k16(pb[js], *(const short4v*)vp, o_acc[nt]);
      }
    }
  }
  // l: sum across the 4 quad-groups (j partitions); all i's live at l16
  lrow += __shfl_xor(lrow, 16);
  lrow += __shfl_xor(lrow, 32);
  float linv = 1.f / lrow;
  #pragma unroll
  for (int r = 0; r < 4; r++){
    float li = __shfl(linv, quad*4 + r);      // l for output row i=quad*4+r
    #pragma unroll
    for (int nt = 0; nt < 4; nt++){
      size_t row = (size_t)(b*S_ + i0 + w*16 + quad*4 + r);
      ctx[row*D_ + h*DH_ + nt*16 + l16] = f2b(o_acc[nt][r] * li);
    }
  }
}
#else
// ---------------- flash attention v7 fallback (no 16x16x16 bf16 builtin) ----------------
#define PPS 68
__global__ __launch_bounds__(256, 4) void flash_kernel(const short* __restrict__ q,
                                                       const short* __restrict__ k,
                                                       const short* __restrict__ VT,
                                                       const short* __restrict__ c2p,
                                                       const short* __restrict__ p2c,
                                                       const short* __restrict__ PFAR,
                                                       const signed char* __restrict__ TAB,
                                                       short* __restrict__ ctx){
  __shared__ short k_lds[64*64];
  __shared__ short v_lds[64*64];
  __shared__ short c2p_lds[64][72];
  __shared__ short pp_lds[64][PPS];
  __shared__ signed char tab[2048];
  int bh = blockIdx.x, it = blockIdx.y;
  int b = bh >> 3, h = bh & 7;
  int i0 = it * 64;
  int tid = threadIdx.x, w = tid >> 6, lane = tid & 63, quad = lane >> 4, l16 = lane & 15;
  ((unsigned long long*)tab)[tid] = ((const unsigned long long*)TAB)[tid];
  #pragma unroll
  for (int i = 0; i < 2; i++){
    int c = i*256 + tid;
    int r = c >> 3, cc = (c & 7) * 8;
    *(int4v*)&c2p_lds[r][cc] = *(const int4v*)(c2p + (size_t)(b*S_ + i0 + r)*D_ + h*DH_ + cc);
  }
  short8 qf0, qf1;
  {
    size_t row = (size_t)(b*S_ + i0 + w*16 + l16);
    qf0 = *(const short8*)(q + row*D_ + h*DH_ +      quad*8);
    qf1 = *(const short8*)(q + row*D_ + h*DH_ + 32 + quad*8);
  }
  const short* Kbase  = k   + (size_t)(b*S_)*D_ + h*DH_;
  const short* VTbase = VT  + (size_t)(b*H_ + h)*DH_*S_;
  const short* Pbase  = p2c + (size_t)(b*S_)*D_ + h*DH_;
  const short* Fbase  = PFAR + (size_t)bh*2048;
  int lr = lane >> 3, lc8 = ((lane & 7) ^ lr) * 8;
  const short* ksrc[2]; const short* vsrc[2];
  #pragma unroll
  for (int i = 0; i < 2; i++){
    int rr = w*16 + i*8 + lr;
    ksrc[i] = Kbase  + (size_t)rr*D_ + lc8;
    vsrc[i] = VTbase + (size_t)rr*S_ + lc8;
  }
  int sx = l16 & 7;
  int st_r = tid >> 3, st_c = (tid & 7) * 8;
  __syncthreads();
  float cpos[4], cneg[4];
  #pragma unroll
  for (int r = 0; r < 4; r++){
    int iloc = w*16 + quad*4 + r;
    cpos[r] = b2f(c2p_lds[iloc][63]);
    cneg[r] = b2f(c2p_lds[iloc][0]);
  }
  f32x4 o_acc[4] = {};
  float lrow[4] = {};
  for (int jt = 0; jt < 16; jt++){
    int j0 = jt * 64;
    bool near = (jt >= it-2 && jt <= it+2);
    int4v ppv0, ppv1;
    if (near){
      ppv0 = *(const int4v*)(Pbase + (size_t)(j0 + st_r     )*D_ + st_c);
      ppv1 = *(const int4v*)(Pbase + (size_t)(j0 + st_r + 32)*D_ + st_c);
    }
    __syncthreads();
    #pragma unroll
    for (int i = 0; i < 2; i++){
      gl16(ksrc[i] + (size_t)j0*D_, &k_lds[(w*16 + i*8)*64]);
      gl16(vsrc[i] + j0,            &v_lds[(w*16 + i*8)*64]);
    }
    if (near){
      *(int4v*)&pp_lds[st_r     ][st_c] = ppv0;
      *(int4v*)&pp_lds[st_r + 32][st_c] = ppv1;
    }
    __syncthreads();
    f32x4 sfr[4];
    #pragma unroll
    for (int nt = 0; nt < 4; nt++){
      int rowb = (nt*16 + l16) << 6;
      f32x4 a = {};
      a = mfma16(qf0, *(const short8*)&k_lds[rowb + ((quad^sx)<<3)], a);
      a = mfma16(qf1, *(const short8*)&k_lds[rowb + (((quad+4)^sx)<<3)], a);
      sfr[nt] = a;
    }
    float pval[4][4];
    if (near){
      #pragma unroll
      for (int nt = 0; nt < 4; nt++){
        int jloc = nt*16 + l16;
        #pragma unroll
        for (int r = 0; r < 4; r++){
          int iloc = w*16 + quad*4 + r;
          int idx  = tab[(i0 + iloc) - (j0 + jloc) + 1023];
          float p = __expf(sfr[nt][r] + b2f(c2p_lds[iloc][idx]) + b2f(pp_lds[jloc][idx]));
          pval[nt][r] = p;
          lrow[r] += p;
        }
      }
      __syncthreads();
    } else {
      const float* cP = (jt < it) ? cpos : cneg;
      const short* fcol = Fbase + ((jt < it) ? 1024 : 0) + j0;
      #pragma unroll
      for (int nt = 0; nt < 4; nt++){
        float pv = b2f(fcol[nt*16 + l16]);
        #pragma unroll
        for (int r = 0; r < 4; r++){
          float p = __expf(sfr[nt][r] + cP[r] + pv);
          pval[nt][r] = p;
          lrow[r] += p;
        }
      }
    }
    #pragma unroll
    for (int nt = 0; nt < 4; nt++)
      #pragma unroll
      for (int r = 0; r < 4; r++)
        pp_lds[w*16 + quad*4 + r][nt*16 + l16] = f2b(pval[nt][r]);
    short8 pf0 = *(const short8*)&pp_lds[w*16 + l16][     quad*8];
    short8 pf1 = *(const short8*)&pp_lds[w*16 + l16][32 + quad*8];
    #pragma unroll
    for (int nt = 0; nt < 4; nt++){
      int rowb = (nt*16 + l16) << 6;
      o_acc[nt] = mfma16(pf0, *(const short8*)&v_lds[rowb + ((quad^sx)<<3)], o_acc[nt]);
      o_acc[nt] = mfma16(pf1, *(const short8*)&v_lds[rowb + (((quad+4)^sx)<<3)], o_acc[nt]);
    }
  }
  #pragma unroll
  for (int r = 0; r < 4; r++){
    #pragma unroll
    for (int off = 8; off; off >>= 1) lrow[r] += __shfl_xor(lrow[r], off);
  }
  #pragma unroll
  for (int nt = 0; nt < 4; nt++)
    #pragma unroll
    for (int r = 0; r < 4; r++){
      size_t row = (size_t)(b*S_ + i0 + w*16 + quad*4 + r);
      ctx[row*D_ + h*DH_ + nt*16 + l16] = f2b(o_acc[nt][r] / lrow[r]);
    }
}
#endif

// ---------------- workspace layout (bytes) — high-water 55,511,040 (~52.9 MB) ----------------
static const size_t OFF_XN   = 0;           // bf16 8192x512  (alias: VT)
static const size_t OFF_Q    = 8388608;     // bf16 8192x512  (alias: FFH lo)
static const size_t OFF_K    = 16777216;    // bf16 8192x512  (alias: FFH hi)
static const size_t OFF_V    = 25165824;    // bf16 8192x512  (alias: CTX)
static const size_t OFF_C2P  = 33554432;    // bf16 8192x512  (alias: DWS)
static const size_t OFF_P2C  = 41943040;    // bf16 8192x512
static const size_t OFF_WPW  = 50331648;    // bf16 512x512
static const size_t OFF_WQ   = 50855936;    // WQ/WK/WV contiguous = [1536,512]
static const size_t OFF_WK   = 51380224;
static const size_t OFF_WV   = 51904512;
static const size_t OFF_WO   = 52428800;
static const size_t OFF_W1   = 52953088;    // bf16 1024x512
static const size_t OFF_W2   = 54001664;    // bf16 512x1024
static const size_t OFF_REL  = 55050240;    // bf16 64x512
static const size_t OFF_POSK = 55115776;    // bf16 64x512
static const size_t OFF_POSQ = 55181312;    // bf16 64x512
static const size_t OFF_TAB  = 55246848;    // int8 2048
static const size_t OFF_PFAR = 55248896;    // bf16 64*2*1024 = 256 KB

extern "C" void kernel_launch(void* const* d_in, const int* in_sizes, int n_in,
                              void* d_out, int out_size, void* d_ws, size_t ws_size,
                              hipStream_t stream){
  const float* x    = (const float*)d_in[0];
  const float* ln1g = (const float*)d_in[1];
  const float* ln1b = (const float*)d_in[2];
  const float* dww  = (const float*)d_in[3];
  const float* dwb  = (const float*)d_in[4];
  const float* pww  = (const float*)d_in[5];
  const float* pwb  = (const float*)d_in[6];
  const float* ln2g = (const float*)d_in[7];
  const float* ln2b = (const float*)d_in[8];
  const float* qw   = (const float*)d_in[9];
  const float* qb   = (const float*)d_in[10];
  const float* kw   = (const float*)d_in[11];
  const float* kb   = (const float*)d_in[12];
  const float* vw   = (const float*)d_in[13];
  const float* vb   = (const float*)d_in[14];
  const float* ow   = (const float*)d_in[15];
  const float* ob   = (const float*)d_in[16];
  const float* rel  = (const float*)d_in[17];
  const float* ln3g = (const float*)d_in[18];
  const float* ln3b = (const float*)d_in[19];
  const float* w1   = (const float*)d_in[20];
  const float* b1   = (const float*)d_in[21];
  const float* w2   = (const float*)d_in[22];
  const float* b2   = (const float*)d_in[23];
  float* out = (float*)d_out;
  char* ws = (char*)d_ws;

  short* XN   = (short*)(ws + OFF_XN);
  short* Q    = (short*)(ws + OFF_Q);
  short* Kb_  = (short*)(ws + OFF_K);
  short* V    = (short*)(ws + OFF_V);
  short* C2P  = (short*)(ws + OFF_C2P);
  short* P2C  = (short*)(ws + OFF_P2C);
  short* WPW  = (short*)(ws + OFF_WPW);
  short* WQ   = (short*)(ws + OFF_WQ);
  short* WK   = (short*)(ws + OFF_WK);
  short* WV   = (short*)(ws + OFF_WV);
  short* WO   = (short*)(ws + OFF_WO);
  short* W1B  = (short*)(ws + OFF_W1);
  short* W2B  = (short*)(ws + OFF_W2);
  short* RELB = (short*)(ws + OFF_REL);
  short* POSK = (short*)(ws + OFF_POSK);
  short* POSQ = (short*)(ws + OFF_POSQ);
  signed char* TAB = (signed char*)(ws + OFF_TAB);
  short* PFAR = (short*)(ws + OFF_PFAR);
  short* DWS  = C2P;     // alias
  short* VT   = XN;      // alias
  short* CTX  = V;       // alias
  short* FFH  = Q;       // alias (16 MB over Q+K)

  // fused weight conversions + bucket table
  F2B8 fa;
  fa.s[0]=pww; fa.d[0]=WPW; fa.n[0]=262144;
  fa.s[1]=qw;  fa.d[1]=WQ;  fa.n[1]=262144;
  fa.s[2]=kw;  fa.d[2]=WK;  fa.n[2]=262144;
  fa.s[3]=vw;  fa.d[3]=WV;  fa.n[3]=262144;
  fa.s[4]=ow;  fa.d[4]=WO;  fa.n[4]=262144;
  fa.s[5]=w1;  fa.d[5]=W1B; fa.n[5]=524288;
  fa.s[6]=w2;  fa.d[6]=W2B; fa.n[6]=524288;
  fa.s[7]=rel; fa.d[7]=RELB;fa.n[7]=32768;
  f2b8_kernel<<<dim3(512,8), 256, 0, stream>>>(fa);
  tab_kernel<<<8, 256, 0, stream>>>(TAB);

  // conv block: out = x + pw(silu(dwconv(ln1(x))))
  ln_kernel<<<BS_, 128, 0, stream>>>(x, ln1g, ln1b, XN);
  dwconv_kernel<<<2048, 256, 0, stream>>>(XN, dww, dwb, DWS);
  gemm_gl<false,true,true,false><<<dim3(64,8), 256, 0, stream>>>(
      DWS, WPW, pwb, x, out, nullptr, BS_, 512, 512);

  // attention block
  ln_kernel<<<BS_, 128, 0, stream>>>(out, ln2g, ln2b, XN);
  gemm_qkv2<<<dim3(64,12), 256, 0, stream>>>(
      XN, WQ, qb, kb, vb, Q, Kb_, V, BS_, 512);
  gemm_pos<<<8, 256, 0, stream>>>(RELB, WK, kb, POSK, 1.f,    512, 512);
  gemm_pos<<<8, 256, 0, stream>>>(RELB, WQ, qb, POSQ, SCALE_, 512, 512);
  posbias_kernel<<<dim3(128,8), 256, 0, stream>>>(Q, Kb_, POSK, POSQ, C2P, P2C, PFAR);
  vtrans_kernel<<<dim3(16,8,8), 256, 0, stream>>>(V, VT);
  flash_kernel<<<dim3(64,16), 256, 0, stream>>>(Q, Kb_, VT, C2P, P2C, PFAR, TAB, CTX);
  gemm_gl<false,true,true,false><<<dim3(64,8), 256, 0, stream>>>(
      CTX, WO, ob, out, out, nullptr, BS_, 512, 512);

  // FFN block: out += w2 @ silu(w1 @ ln3(out))
  ln_kernel<<<BS_, 128, 0, stream>>>(out, ln3g, ln3b, XN);
  gemm_gl2<true,true><<<dim3(64,8), 256, 0, stream>>>(
      XN, W1B, b1, FFH, BS_, 1024, 512);
  gemm_gl<false,true,true,false><<<dim3(64,8), 256, 0, stream>>>(
      FFH, W2B, b2, out, out, nullptr, BS_, 512, 1024);
}